// Round 6
// baseline (2955.755 us; speedup 1.0000x reference)
//
#include <hip/hip_runtime.h>

#define D 128
#define RB 64           // rows per bucket
#define NBKMAX 1024     // max buckets (N <= 65536)
#define SCHUNKS 64      // scatter/hist chunk blocks

// ---------------- setup: transpose weights + fold Wc = Vkx - 2*Wkx ----------------
__global__ __launch_bounds__(256) void setup_weights(
    const float* __restrict__ Uky, const float* __restrict__ Ukx,
    const float* __restrict__ Vky, const float* __restrict__ Vkx,
    const float* __restrict__ Wkx, const float* __restrict__ Vkx_b,
    const float* __restrict__ Wkx_b,
    float* __restrict__ UkyT, float* __restrict__ UkxT,
    float* __restrict__ VkyT, float* __restrict__ WcT, float* __restrict__ bc)
{
    const int m = blockIdx.x;
    const float* src = (m == 0) ? Uky : (m == 1) ? Ukx : (m == 2) ? Vky : nullptr;
    float* dst = (m == 0) ? UkyT : (m == 1) ? UkxT : (m == 2) ? VkyT : WcT;
    for (int i = threadIdx.x; i < D * D; i += 256) {
        int k = i >> 7, d = i & 127;
        float v;
        if (m == 3) v = Vkx[d * D + k] - 2.0f * Wkx[d * D + k];
        else        v = src[d * D + k];
        dst[i] = v;
    }
    if (m == 3 && threadIdx.x < D)
        bc[threadIdx.x] = Vkx_b[threadIdx.x] - 2.0f * Wkx_b[threadIdx.x];
}

// ---------------- fused GEMM v2 (pre-transposed W) ----------------
template <int EPI>
__global__ __launch_bounds__(256) void gemm_v2(
    const float* __restrict__ X, const float* __restrict__ WT,
    const float* __restrict__ bias, const float* __restrict__ colvec,
    const float* __restrict__ spout, const float* __restrict__ scal,
    float* __restrict__ out, int N)
{
    __shared__ float Xs[64][D + 4];
    __shared__ float Wt[64][D + 4];
    const int t = threadIdx.x;
    const int block_row = blockIdx.x * 64;

#pragma unroll
    for (int i = 0; i < 8; ++i) {
        int f = t + i * 256;
        int r = f >> 5;
        int k4 = (f & 31) << 2;
        float4 g = make_float4(0.f, 0.f, 0.f, 0.f);
        int row = block_row + r;
        if (row < N) g = *reinterpret_cast<const float4*>(&X[(size_t)row * D + k4]);
        *reinterpret_cast<float4*>(&Xs[r][k4]) = g;
    }

    const int cg = t & 15;
    const int rp = t >> 4;
    const int r0 = rp * 4;
    const int c0 = cg * 4, c1 = 64 + cg * 4;

    float acc[4][8] = {{0.f}};

    for (int kb = 0; kb < D; kb += 64) {
        __syncthreads();
#pragma unroll
        for (int i = 0; i < 8; ++i) {
            int f = t + i * 256;
            int kk = f >> 5;
            int d4 = (f & 31) << 2;
            float4 g = *reinterpret_cast<const float4*>(&WT[(size_t)(kb + kk) * D + d4]);
            *reinterpret_cast<float4*>(&Wt[kk][d4]) = g;
        }
        __syncthreads();
#pragma unroll 2
        for (int k4 = 0; k4 < 64; k4 += 4) {
            float4 xr[4];
#pragma unroll
            for (int j = 0; j < 4; ++j)
                xr[j] = *reinterpret_cast<const float4*>(&Xs[r0 + j][kb + k4]);
#pragma unroll
            for (int q = 0; q < 4; ++q) {
                const float4 w0 = *reinterpret_cast<const float4*>(&Wt[k4 + q][c0]);
                const float4 w1 = *reinterpret_cast<const float4*>(&Wt[k4 + q][c1]);
#pragma unroll
                for (int j = 0; j < 4; ++j) {
                    const float xv = (q == 0) ? xr[j].x : (q == 1) ? xr[j].y
                                   : (q == 2) ? xr[j].z : xr[j].w;
                    acc[j][0] += xv * w0.x; acc[j][1] += xv * w0.y;
                    acc[j][2] += xv * w0.z; acc[j][3] += xv * w0.w;
                    acc[j][4] += xv * w1.x; acc[j][5] += xv * w1.y;
                    acc[j][6] += xv * w1.z; acc[j][7] += xv * w1.w;
                }
            }
        }
    }

    const float sc = (EPI == 0) ? 0.f : scal[0];
    const float4 bias0 = *reinterpret_cast<const float4*>(&bias[c0]);
    const float4 bias1 = *reinterpret_cast<const float4*>(&bias[c1]);

#pragma unroll
    for (int j = 0; j < 4; ++j) {
        const int row = block_row + r0 + j;
        if (row >= N) continue;
        const float cv = (EPI == 0) ? 0.f : colvec[row];
#pragma unroll
        for (int h = 0; h < 2; ++h) {
            const int col = (h == 0) ? c0 : c1;
            const float4 bs = (h == 0) ? bias0 : bias1;
            float4 res;
            res.x = acc[j][h * 4 + 0] + bs.x;
            res.y = acc[j][h * 4 + 1] + bs.y;
            res.z = acc[j][h * 4 + 2] + bs.z;
            res.w = acc[j][h * 4 + 3] + bs.w;
            if (EPI == 1) {
                float4 sp = *reinterpret_cast<const float4*>(&spout[(size_t)row * D + col]);
                res.x = fmaxf(res.x - sc * (cv - sp.x), 0.f);
                res.y = fmaxf(res.y - sc * (cv - sp.y), 0.f);
                res.z = fmaxf(res.z - sc * (cv - sp.z), 0.f);
                res.w = fmaxf(res.w - sc * (cv - sp.w), 0.f);
            } else if (EPI == 2) {
                float4 sp = *reinterpret_cast<const float4*>(&spout[(size_t)row * D + col]);
                res.x = fmaxf(res.x - sc * (cv + sp.x), 0.f);
                res.y = fmaxf(res.y - sc * (cv + sp.y), 0.f);
                res.z = fmaxf(res.z - sc * (cv + sp.z), 0.f);
                res.w = fmaxf(res.w - sc * (cv + sp.w), 0.f);
            }
            *reinterpret_cast<float4*>(&out[(size_t)row * D + col]) = res;
        }
    }
}

// ---------------- bucket histogram (LDS-local, one global merge) ----------------
__global__ __launch_bounds__(256) void hist_buckets(
    const int* __restrict__ rows, const int* __restrict__ cols,
    int* __restrict__ cntR, int* __restrict__ cntC, int nnz, int nbk, int ce)
{
    __shared__ int lhR[NBKMAX], lhC[NBKMAX];
    for (int i = threadIdx.x; i < nbk; i += 256) { lhR[i] = 0; lhC[i] = 0; }
    __syncthreads();
    const int e0 = blockIdx.x * ce, e1 = min(nnz, e0 + ce);
    for (int e = e0 + threadIdx.x; e < e1; e += 256) {
        atomicAdd(&lhR[rows[e] >> 6], 1);
        atomicAdd(&lhC[cols[e] >> 6], 1);
    }
    __syncthreads();
    for (int i = threadIdx.x; i < nbk; i += 256) {
        if (lhR[i]) atomicAdd(&cntR[i], lhR[i]);
        if (lhC[i]) atomicAdd(&cntC[i], lhC[i]);
    }
}

// ---------------- bucket scan (16-record aligned regions) ----------------
__global__ __launch_bounds__(256) void scan_buckets(
    const int* __restrict__ cntR, const int* __restrict__ cntC,
    int* __restrict__ goffR, int* __restrict__ gcurR,
    int* __restrict__ goffC, int* __restrict__ gcurC, int nbk)
{
    const int* cnt = blockIdx.x ? cntC : cntR;
    int* goff = blockIdx.x ? goffC : goffR;
    int* gcur = blockIdx.x ? gcurC : gcurR;
    __shared__ int s[256];
    const int t = threadIdx.x;
    const int base = t * 4;
    int loc[4]; int sum = 0;
#pragma unroll
    for (int u = 0; u < 4; ++u) {
        int idx = base + u;
        int v = (idx < nbk) ? ((cnt[idx] + 15) & ~15) : 0;   // 128B-aligned regions
        loc[u] = sum; sum += v;
    }
    s[t] = sum;
    __syncthreads();
#pragma unroll
    for (int d = 1; d < 256; d <<= 1) {
        int tv = (t >= d) ? s[t - d] : 0;
        __syncthreads();
        s[t] += tv;
        __syncthreads();
    }
    int excl = s[t] - sum;
#pragma unroll
    for (int u = 0; u < 4; ++u) {
        int idx = base + u;
        if (idx < nbk) { int o = excl + loc[u]; goff[idx] = o; gcur[idx] = o; }
    }
}

// ---------------- chunked reservation scatter ----------------
// Per block: LDS-hist its chunk, reserve one contiguous run per (chunk,bucket)
// with ONE global atomic per bucket, then write records into the run.
// Every output line is written by exactly one block (= one XCD) -> lines
// assemble in local L2, killing cross-XCD write amplification.
// record = { (dest%64)<<16 | gather_col , val_bits }, 8 B (needs N < 65536).
__global__ __launch_bounds__(256) void scatter_buckets(
    const int* __restrict__ rows, const int* __restrict__ cols,
    const float* __restrict__ vals,
    int* __restrict__ gcurR, int2* __restrict__ recR,
    int* __restrict__ gcurC, int2* __restrict__ recC,
    int nnz, int nbk, int ce)
{
    __shared__ int lhR[NBKMAX], gpR[NBKMAX], lcR[NBKMAX];
    __shared__ int lhC[NBKMAX], gpC[NBKMAX], lcC[NBKMAX];
    for (int i = threadIdx.x; i < nbk; i += 256) { lhR[i] = 0; lhC[i] = 0; }
    __syncthreads();
    const int e0 = blockIdx.x * ce, e1 = min(nnz, e0 + ce);
    for (int e = e0 + threadIdx.x; e < e1; e += 256) {
        atomicAdd(&lhR[rows[e] >> 6], 1);
        atomicAdd(&lhC[cols[e] >> 6], 1);
    }
    __syncthreads();
    for (int i = threadIdx.x; i < nbk; i += 256) {
        int h = lhR[i];
        if (h) gpR[i] = atomicAdd(&gcurR[i], h);
        lcR[i] = 0;
        h = lhC[i];
        if (h) gpC[i] = atomicAdd(&gcurC[i], h);
        lcC[i] = 0;
    }
    __syncthreads();
    for (int e = e0 + threadIdx.x; e < e1; e += 256) {
        int r = rows[e], c = cols[e];
        int vb = __float_as_int(vals[e]);
        int bR = r >> 6, bC = c >> 6;
        int pR = gpR[bR] + atomicAdd(&lcR[bR], 1);
        recR[pR] = make_int2(((r & 63) << 16) | c, vb);
        int pC = gpC[bC] + atomicAdd(&lcC[bC], 1);
        recC[pC] = make_int2(((c & 63) << 16) | r, vb);
    }
}

// ---------------- bucket SpMM: LDS accumulators, wave-per-edge ----------------
__global__ __launch_bounds__(256) void spmm_bucket(
    const int2* __restrict__ recs, const int* __restrict__ goff,
    const int* __restrict__ cnt, const float* __restrict__ X,
    float* __restrict__ out, int N)
{
    __shared__ float acc[RB * D];   // 32 KB
    const int t = threadIdx.x;
    const int b = blockIdx.x;
#pragma unroll
    for (int i = t; i < RB * D / 4; i += 256)
        reinterpret_cast<float4*>(acc)[i] = make_float4(0.f, 0.f, 0.f, 0.f);
    __syncthreads();

    const int s = goff[b];
    const int L = cnt[b];
    const int wv = t >> 6;
    const int l2 = (t & 63) * 2;

    int i = wv;
    for (; i + 4 < L; i += 8) {                 // unroll 2 (stride 4 waves)
        int2 pa = recs[s + i];
        int2 pb = recs[s + i + 4];
        float2 xa = *reinterpret_cast<const float2*>(&X[(size_t)(pa.x & 0xFFFF) * D + l2]);
        float2 xb = *reinterpret_cast<const float2*>(&X[(size_t)(pb.x & 0xFFFF) * D + l2]);
        float va = __int_as_float(pa.y), vb = __int_as_float(pb.y);
        int da = (pa.x >> 16) * D + l2;
        int db = (pb.x >> 16) * D + l2;
        atomicAdd(&acc[da + 0], va * xa.x);
        atomicAdd(&acc[da + 1], va * xa.y);
        atomicAdd(&acc[db + 0], vb * xb.x);
        atomicAdd(&acc[db + 1], vb * xb.y);
    }
    if (i < L) {
        int2 pa = recs[s + i];
        float2 xa = *reinterpret_cast<const float2*>(&X[(size_t)(pa.x & 0xFFFF) * D + l2]);
        float va = __int_as_float(pa.y);
        int da = (pa.x >> 16) * D + l2;
        atomicAdd(&acc[da + 0], va * xa.x);
        atomicAdd(&acc[da + 1], va * xa.y);
    }
    __syncthreads();

    const int base_row = b * RB;
#pragma unroll
    for (int i2 = t; i2 < RB * (D / 4); i2 += 256) {
        int r = i2 >> 5;
        int cq = (i2 & 31) << 2;
        int row = base_row + r;
        if (row < N)
            *reinterpret_cast<float4*>(&out[(size_t)row * D + cq]) =
                *reinterpret_cast<const float4*>(&acc[r * D + cq]);
    }
}

// ---------------- atomic fallback ----------------
__global__ __launch_bounds__(256) void spmm_atomic(
    const float* __restrict__ vals, const int* __restrict__ orow,
    const int* __restrict__ gcol, const float* __restrict__ Xm,
    float* __restrict__ outm, int nnz)
{
    const int gwave = (blockIdx.x * 256 + threadIdx.x) >> 6;
    const int lane = threadIdx.x & 63;
    const int e0 = gwave * 4;
#pragma unroll
    for (int i = 0; i < 4; ++i) {
        int e = e0 + i;
        if (e >= nnz) break;
        float v = vals[e];
        int r = orow[e];
        int c = gcol[e];
        float2 xv = *reinterpret_cast<const float2*>(&Xm[(size_t)c * D + lane * 2]);
        unsafeAtomicAdd(&outm[(size_t)r * D + lane * 2 + 0], v * xv.x);
        unsafeAtomicAdd(&outm[(size_t)r * D + lane * 2 + 1], v * xv.y);
    }
}

extern "C" void kernel_launch(void* const* d_in, const int* in_sizes, int n_in,
                              void* d_out, int out_size, void* d_ws, size_t ws_size,
                              hipStream_t stream) {
    const float* x      = (const float*)d_in[0];
    const float* y      = (const float*)d_in[1];
    const float* c      = (const float*)d_in[2];
    const float* b      = (const float*)d_in[3];
    const float* A_vals = (const float*)d_in[4];
    const int*   A_rows = (const int*)d_in[5];
    const int*   A_cols = (const int*)d_in[6];
    const float* Ukx_w  = (const float*)d_in[7];
    const float* Ukx_b  = (const float*)d_in[8];
    const float* Uky_w  = (const float*)d_in[9];
    const float* Uky_b  = (const float*)d_in[10];
    const float* tau    = (const float*)d_in[11];
    const float* Vky_w  = (const float*)d_in[12];
    const float* Vky_b  = (const float*)d_in[13];
    const float* Wkx_w  = (const float*)d_in[14];
    const float* Wkx_b  = (const float*)d_in[15];
    const float* Vkx_w  = (const float*)d_in[16];
    const float* Vkx_b  = (const float*)d_in[17];
    const float* sigma  = (const float*)d_in[18];

    const int N   = in_sizes[0] / D;        // 50000
    const int nnz = in_sizes[4];            // 1.6M
    const int nbk = (N + RB - 1) / RB;      // 782

    float* out_x = (float*)d_out;
    float* out_y = out_x + (size_t)N * D;

    const int gemm_grid = (N + 63) / 64;

    // ws layout: tmp[N*D] | UkyT|UkxT|VkyT|WcT|bc | recR pool | recC pool |
    //            cntR cntC goffR goffC gcurR gcurC  (each nbk ints)
    float* tmp  = (float*)d_ws;
    float* UkyT = tmp + (size_t)N * D;
    float* UkxT = UkyT + D * D;
    float* VkyT = UkxT + D * D;
    float* WcT  = VkyT + D * D;
    float* bc   = WcT + D * D;
    size_t pool = (size_t)nnz + 16 * (size_t)nbk;
    int2* recR  = (int2*)(bc + D);          // byte offset divisible by 8
    int2* recC  = recR + pool;
    int* cntR  = (int*)(recC + pool);
    int* cntC  = cntR + nbk;
    int* goffR = cntC + nbk;
    int* goffC = goffR + nbk;
    int* gcurR = goffC + nbk;
    int* gcurC = gcurR + nbk;

    size_t need = ((size_t)N * D + 4 * D * D + D + 6 * (size_t)nbk) * 4 + 2 * pool * 8;

    setup_weights<<<4, 256, 0, stream>>>(Uky_w, Ukx_w, Vky_w, Vkx_w, Wkx_w,
                                         Vkx_b, Wkx_b, UkyT, UkxT, VkyT, WcT, bc);

    if (N < 65536 && nbk <= NBKMAX && ws_size >= need) {
        const int ce = (nnz + SCHUNKS - 1) / SCHUNKS;

        // ---- bucket build ----
        hipMemsetAsync(cntR, 0, 2 * (size_t)nbk * sizeof(int), stream);
        hist_buckets<<<SCHUNKS, 256, 0, stream>>>(A_rows, A_cols, cntR, cntC, nnz, nbk, ce);
        scan_buckets<<<2, 256, 0, stream>>>(cntR, cntC, goffR, gcurR, goffC, gcurC, nbk);
        scatter_buckets<<<SCHUNKS, 256, 0, stream>>>(A_rows, A_cols, A_vals,
                                                     gcurR, recR, gcurC, recC, nnz, nbk, ce);

        // uy = y @ Uky^T + b  -> staged in out_y
        gemm_v2<0><<<gemm_grid, 256, 0, stream>>>(y, UkyT, Uky_b, nullptr, nullptr, nullptr, out_y, N);
        // at_uy -> out_x   (grouped by A_cols; gather col = A_rows)
        spmm_bucket<<<nbk, 256, 0, stream>>>(recC, goffC, cntC, out_y, out_x, N);
        // x_new -> out_x (in place)
        gemm_v2<1><<<gemm_grid, 256, 0, stream>>>(x, UkxT, Ukx_b, c, out_x, tau, out_x, N);
        // zx -> tmp
        gemm_v2<0><<<gemm_grid, 256, 0, stream>>>(out_x, WcT, bc, nullptr, nullptr, nullptr, tmp, N);
        // az -> out_y   (grouped by A_rows; gather col = A_cols)
        spmm_bucket<<<nbk, 256, 0, stream>>>(recR, goffR, cntR, tmp, out_y, N);
        // y_new -> out_y (in place)
        gemm_v2<2><<<gemm_grid, 256, 0, stream>>>(y, VkyT, Vky_b, b, out_y, sigma, out_y, N);
    } else {
        // ---- atomic fallback ----
        const int spmm_grid = (nnz + 15) / 16;
        gemm_v2<0><<<gemm_grid, 256, 0, stream>>>(y, UkyT, Uky_b, nullptr, nullptr, nullptr, tmp, N);
        hipMemsetAsync(out_x, 0, (size_t)N * D * sizeof(float), stream);
        spmm_atomic<<<spmm_grid, 256, 0, stream>>>(A_vals, A_cols, A_rows, tmp, out_x, nnz);
        gemm_v2<1><<<gemm_grid, 256, 0, stream>>>(x, UkxT, Ukx_b, c, out_x, tau, out_x, N);
        gemm_v2<0><<<gemm_grid, 256, 0, stream>>>(out_x, WcT, bc, nullptr, nullptr, nullptr, tmp, N);
        hipMemsetAsync(out_y, 0, (size_t)N * D * sizeof(float), stream);
        spmm_atomic<<<spmm_grid, 256, 0, stream>>>(A_vals, A_rows, A_cols, tmp, out_y, nnz);
        gemm_v2<2><<<gemm_grid, 256, 0, stream>>>(y, VkyT, Vky_b, b, out_y, sigma, out_y, N);
    }
}

// Round 7
// 505.588 us; speedup vs baseline: 5.8462x; 5.8462x over previous
//
#include <hip/hip_runtime.h>

#define D 128
#define RB 64           // rows per bucket
#define NBKMAX 1024     // max buckets (N <= 65536)
#define SCHUNKS 64      // scatter/hist chunk blocks

// ---------------- setup: transpose weights + fold Wc = Vkx - 2*Wkx ----------------
__global__ __launch_bounds__(256) void setup_weights(
    const float* __restrict__ Uky, const float* __restrict__ Ukx,
    const float* __restrict__ Vky, const float* __restrict__ Vkx,
    const float* __restrict__ Wkx, const float* __restrict__ Vkx_b,
    const float* __restrict__ Wkx_b,
    float* __restrict__ UkyT, float* __restrict__ UkxT,
    float* __restrict__ VkyT, float* __restrict__ WcT, float* __restrict__ bc)
{
    const int m = blockIdx.x;
    const float* src = (m == 0) ? Uky : (m == 1) ? Ukx : (m == 2) ? Vky : nullptr;
    float* dst = (m == 0) ? UkyT : (m == 1) ? UkxT : (m == 2) ? VkyT : WcT;
    for (int i = threadIdx.x; i < D * D; i += 256) {
        int k = i >> 7, d = i & 127;
        float v;
        if (m == 3) v = Vkx[d * D + k] - 2.0f * Wkx[d * D + k];
        else        v = src[d * D + k];
        dst[i] = v;
    }
    if (m == 3 && threadIdx.x < D)
        bc[threadIdx.x] = Vkx_b[threadIdx.x] - 2.0f * Wkx_b[threadIdx.x];
}

// ---------------- fused GEMM v2 (pre-transposed W) ----------------
template <int EPI>
__global__ __launch_bounds__(256) void gemm_v2(
    const float* __restrict__ X, const float* __restrict__ WT,
    const float* __restrict__ bias, const float* __restrict__ colvec,
    const float* __restrict__ spout, const float* __restrict__ scal,
    float* __restrict__ out, int N)
{
    __shared__ float Xs[64][D + 4];
    __shared__ float Wt[64][D + 4];
    const int t = threadIdx.x;
    const int block_row = blockIdx.x * 64;

#pragma unroll
    for (int i = 0; i < 8; ++i) {
        int f = t + i * 256;
        int r = f >> 5;
        int k4 = (f & 31) << 2;
        float4 g = make_float4(0.f, 0.f, 0.f, 0.f);
        int row = block_row + r;
        if (row < N) g = *reinterpret_cast<const float4*>(&X[(size_t)row * D + k4]);
        *reinterpret_cast<float4*>(&Xs[r][k4]) = g;
    }

    const int cg = t & 15;
    const int rp = t >> 4;
    const int r0 = rp * 4;
    const int c0 = cg * 4, c1 = 64 + cg * 4;

    float acc[4][8] = {{0.f}};

    for (int kb = 0; kb < D; kb += 64) {
        __syncthreads();
#pragma unroll
        for (int i = 0; i < 8; ++i) {
            int f = t + i * 256;
            int kk = f >> 5;
            int d4 = (f & 31) << 2;
            float4 g = *reinterpret_cast<const float4*>(&WT[(size_t)(kb + kk) * D + d4]);
            *reinterpret_cast<float4*>(&Wt[kk][d4]) = g;
        }
        __syncthreads();
#pragma unroll 2
        for (int k4 = 0; k4 < 64; k4 += 4) {
            float4 xr[4];
#pragma unroll
            for (int j = 0; j < 4; ++j)
                xr[j] = *reinterpret_cast<const float4*>(&Xs[r0 + j][kb + k4]);
#pragma unroll
            for (int q = 0; q < 4; ++q) {
                const float4 w0 = *reinterpret_cast<const float4*>(&Wt[k4 + q][c0]);
                const float4 w1 = *reinterpret_cast<const float4*>(&Wt[k4 + q][c1]);
#pragma unroll
                for (int j = 0; j < 4; ++j) {
                    const float xv = (q == 0) ? xr[j].x : (q == 1) ? xr[j].y
                                   : (q == 2) ? xr[j].z : xr[j].w;
                    acc[j][0] += xv * w0.x; acc[j][1] += xv * w0.y;
                    acc[j][2] += xv * w0.z; acc[j][3] += xv * w0.w;
                    acc[j][4] += xv * w1.x; acc[j][5] += xv * w1.y;
                    acc[j][6] += xv * w1.z; acc[j][7] += xv * w1.w;
                }
            }
        }
    }

    const float sc = (EPI == 0) ? 0.f : scal[0];
    const float4 bias0 = *reinterpret_cast<const float4*>(&bias[c0]);
    const float4 bias1 = *reinterpret_cast<const float4*>(&bias[c1]);

#pragma unroll
    for (int j = 0; j < 4; ++j) {
        const int row = block_row + r0 + j;
        if (row >= N) continue;
        const float cv = (EPI == 0) ? 0.f : colvec[row];
#pragma unroll
        for (int h = 0; h < 2; ++h) {
            const int col = (h == 0) ? c0 : c1;
            const float4 bs = (h == 0) ? bias0 : bias1;
            float4 res;
            res.x = acc[j][h * 4 + 0] + bs.x;
            res.y = acc[j][h * 4 + 1] + bs.y;
            res.z = acc[j][h * 4 + 2] + bs.z;
            res.w = acc[j][h * 4 + 3] + bs.w;
            if (EPI == 1) {
                float4 sp = *reinterpret_cast<const float4*>(&spout[(size_t)row * D + col]);
                res.x = fmaxf(res.x - sc * (cv - sp.x), 0.f);
                res.y = fmaxf(res.y - sc * (cv - sp.y), 0.f);
                res.z = fmaxf(res.z - sc * (cv - sp.z), 0.f);
                res.w = fmaxf(res.w - sc * (cv - sp.w), 0.f);
            } else if (EPI == 2) {
                float4 sp = *reinterpret_cast<const float4*>(&spout[(size_t)row * D + col]);
                res.x = fmaxf(res.x - sc * (cv + sp.x), 0.f);
                res.y = fmaxf(res.y - sc * (cv + sp.y), 0.f);
                res.z = fmaxf(res.z - sc * (cv + sp.z), 0.f);
                res.w = fmaxf(res.w - sc * (cv + sp.w), 0.f);
            }
            *reinterpret_cast<float4*>(&out[(size_t)row * D + col]) = res;
        }
    }
}

// ---------------- bucket histogram (LDS-local, one global merge) ----------------
__global__ __launch_bounds__(256) void hist_buckets(
    const int* __restrict__ rows, const int* __restrict__ cols,
    int* __restrict__ cntR, int* __restrict__ cntC, int nnz, int nbk, int ce)
{
    __shared__ int lhR[NBKMAX], lhC[NBKMAX];
    for (int i = threadIdx.x; i < nbk; i += 256) { lhR[i] = 0; lhC[i] = 0; }
    __syncthreads();
    const int e0 = blockIdx.x * ce, e1 = min(nnz, e0 + ce);
    for (int e = e0 + threadIdx.x; e < e1; e += 256) {
        atomicAdd(&lhR[rows[e] >> 6], 1);
        atomicAdd(&lhC[cols[e] >> 6], 1);
    }
    __syncthreads();
    for (int i = threadIdx.x; i < nbk; i += 256) {
        if (lhR[i]) atomicAdd(&cntR[i], lhR[i]);
        if (lhC[i]) atomicAdd(&cntC[i], lhC[i]);
    }
}

// ---------------- bucket scan ----------------
__global__ __launch_bounds__(256) void scan_buckets(
    const int* __restrict__ cntR, const int* __restrict__ cntC,
    int* __restrict__ goffR, int* __restrict__ gcurR,
    int* __restrict__ goffC, int* __restrict__ gcurC, int nbk)
{
    const int* cnt = blockIdx.x ? cntC : cntR;
    int* goff = blockIdx.x ? goffC : goffR;
    int* gcur = blockIdx.x ? gcurC : gcurR;
    __shared__ int s[256];
    const int t = threadIdx.x;
    const int base = t * 4;
    int loc[4]; int sum = 0;
#pragma unroll
    for (int u = 0; u < 4; ++u) {
        int idx = base + u;
        int v = (idx < nbk) ? cnt[idx] : 0;
        loc[u] = sum; sum += v;
    }
    s[t] = sum;
    __syncthreads();
#pragma unroll
    for (int d = 1; d < 256; d <<= 1) {
        int tv = (t >= d) ? s[t - d] : 0;
        __syncthreads();
        s[t] += tv;
        __syncthreads();
    }
    int excl = s[t] - sum;
#pragma unroll
    for (int u = 0; u < 4; ++u) {
        int idx = base + u;
        if (idx < nbk) { int o = excl + loc[u]; goff[idx] = o; gcur[idx] = o; }
    }
}

// ---------------- chunked reservation scatter (bucket-granular, cheap) -------------
// record = { (dest%64)<<16 | gather_col , val_bits }, 8 B (needs N < 65536).
__global__ __launch_bounds__(256) void scatter_buckets(
    const int* __restrict__ rows, const int* __restrict__ cols,
    const float* __restrict__ vals,
    int* __restrict__ gcurR, int2* __restrict__ recR,
    int* __restrict__ gcurC, int2* __restrict__ recC,
    int nnz, int nbk, int ce)
{
    __shared__ int lhR[NBKMAX], gpR[NBKMAX], lcR[NBKMAX];
    __shared__ int lhC[NBKMAX], gpC[NBKMAX], lcC[NBKMAX];
    for (int i = threadIdx.x; i < nbk; i += 256) { lhR[i] = 0; lhC[i] = 0; }
    __syncthreads();
    const int e0 = blockIdx.x * ce, e1 = min(nnz, e0 + ce);
    for (int e = e0 + threadIdx.x; e < e1; e += 256) {
        atomicAdd(&lhR[rows[e] >> 6], 1);
        atomicAdd(&lhC[cols[e] >> 6], 1);
    }
    __syncthreads();
    for (int i = threadIdx.x; i < nbk; i += 256) {
        int h = lhR[i];
        if (h) gpR[i] = atomicAdd(&gcurR[i], h);
        lcR[i] = 0;
        h = lhC[i];
        if (h) gpC[i] = atomicAdd(&gcurC[i], h);
        lcC[i] = 0;
    }
    __syncthreads();
    for (int e = e0 + threadIdx.x; e < e1; e += 256) {
        int r = rows[e], c = cols[e];
        int vb = __float_as_int(vals[e]);
        int bR = r >> 6, bC = c >> 6;
        int pR = gpR[bR] + atomicAdd(&lcR[bR], 1);
        recR[pR] = make_int2(((r & 63) << 16) | c, vb);
        int pC = gpC[bC] + atomicAdd(&lcC[bC], 1);
        recC[pC] = make_int2(((c & 63) << 16) | r, vb);
    }
}

// ---------------- per-bucket row sort: bucket records -> row-contiguous pairs ------
// One block per (bucket, grouping). Reads its L2-resident record run twice,
// writes row-sorted pairs + per-row off/len. pairs[i] = (gather_col, val_bits).
__global__ __launch_bounds__(256) void sort_buckets(
    const int2* __restrict__ recR, const int2* __restrict__ recC,
    const int* __restrict__ goffR, const int* __restrict__ cntR,
    const int* __restrict__ goffC, const int* __restrict__ cntC,
    int2* __restrict__ pairsR, int2* __restrict__ pairsC,
    int* __restrict__ offR, int* __restrict__ lenR,
    int* __restrict__ offC, int* __restrict__ lenC, int N)
{
    const bool isC = blockIdx.y;
    const int b = blockIdx.x;
    const int2* rec = isC ? recC : recR;
    int2* pairs = isC ? pairsC : pairsR;
    int* off = isC ? offC : offR;
    int* len = isC ? lenC : lenR;
    const int s = (isC ? goffC : goffR)[b];
    const int L = (isC ? cntC : cntR)[b];
    const int t = threadIdx.x;

    __shared__ int lcnt[RB], lpos[RB], lcur[RB];
    if (t < RB) lcnt[t] = 0;
    __syncthreads();
    for (int i = t; i < L; i += 256)
        atomicAdd(&lcnt[rec[s + i].x >> 16], 1);
    __syncthreads();
    if (t == 0) {
        int run = 0;
#pragma unroll
        for (int r = 0; r < RB; ++r) { lpos[r] = run; run += lcnt[r]; }
    }
    __syncthreads();
    if (t < RB) {
        int row = b * RB + t;
        if (row < N) { off[row] = s + lpos[t]; len[row] = lcnt[t]; }
        lcur[t] = 0;
    }
    __syncthreads();
    for (int i = t; i < L; i += 256) {
        int2 pr = rec[s + i];
        int r = pr.x >> 16;
        int p = lpos[r] + atomicAdd(&lcur[r], 1);
        pairs[s + p] = make_int2(pr.x & 0xFFFF, pr.y);
    }
}

// ---------------- pairs-gather SpMM (wave-per-row, proven round-5) ----------------
__global__ __launch_bounds__(256) void spmm_pairs_v2(
    const int2* __restrict__ pairs, const int* __restrict__ off,
    const int* __restrict__ len, const float* __restrict__ X,
    float* __restrict__ out, int N)
{
    const int row = (blockIdx.x * 256 + threadIdx.x) >> 6;
    if (row >= N) return;
    const int lane = threadIdx.x & 63;
    const int half = lane >> 5;
    const int cq = (lane & 31) << 2;
    const int s = off[row];
    const int L = len[row];

    float4 a0 = make_float4(0.f, 0.f, 0.f, 0.f);
    float4 a1 = make_float4(0.f, 0.f, 0.f, 0.f);
    float4 a2 = make_float4(0.f, 0.f, 0.f, 0.f);
    float4 a3 = make_float4(0.f, 0.f, 0.f, 0.f);

    int i = 0;
    for (; i + 7 < L; i += 8) {
        int2 p0 = pairs[s + i + 0 + half];
        int2 p1 = pairs[s + i + 2 + half];
        int2 p2 = pairs[s + i + 4 + half];
        int2 p3 = pairs[s + i + 6 + half];
        float4 x0 = *reinterpret_cast<const float4*>(&X[(size_t)p0.x * D + cq]);
        float4 x1 = *reinterpret_cast<const float4*>(&X[(size_t)p1.x * D + cq]);
        float4 x2 = *reinterpret_cast<const float4*>(&X[(size_t)p2.x * D + cq]);
        float4 x3 = *reinterpret_cast<const float4*>(&X[(size_t)p3.x * D + cq]);
        float v0 = __int_as_float(p0.y), v1 = __int_as_float(p1.y);
        float v2 = __int_as_float(p2.y), v3 = __int_as_float(p3.y);
        a0.x += v0 * x0.x; a0.y += v0 * x0.y; a0.z += v0 * x0.z; a0.w += v0 * x0.w;
        a1.x += v1 * x1.x; a1.y += v1 * x1.y; a1.z += v1 * x1.z; a1.w += v1 * x1.w;
        a2.x += v2 * x2.x; a2.y += v2 * x2.y; a2.z += v2 * x2.z; a2.w += v2 * x2.w;
        a3.x += v3 * x3.x; a3.y += v3 * x3.y; a3.z += v3 * x3.z; a3.w += v3 * x3.w;
    }
    for (; i < L; i += 2) {
        int e = i + half;
        int2 p = (e < L) ? pairs[s + e] : make_int2(0, 0);
        float v = __int_as_float(p.y);
        float4 xv = *reinterpret_cast<const float4*>(&X[(size_t)p.x * D + cq]);
        a0.x += v * xv.x; a0.y += v * xv.y; a0.z += v * xv.z; a0.w += v * xv.w;
    }

    float4 A;
    A.x = (a0.x + a1.x) + (a2.x + a3.x);
    A.y = (a0.y + a1.y) + (a2.y + a3.y);
    A.z = (a0.z + a1.z) + (a2.z + a3.z);
    A.w = (a0.w + a1.w) + (a2.w + a3.w);
    A.x += __shfl_xor(A.x, 32);
    A.y += __shfl_xor(A.y, 32);
    A.z += __shfl_xor(A.z, 32);
    A.w += __shfl_xor(A.w, 32);
    if (half == 0)
        *reinterpret_cast<float4*>(&out[(size_t)row * D + cq]) = A;
}

// ---------------- atomic fallback ----------------
__global__ __launch_bounds__(256) void spmm_atomic(
    const float* __restrict__ vals, const int* __restrict__ orow,
    const int* __restrict__ gcol, const float* __restrict__ Xm,
    float* __restrict__ outm, int nnz)
{
    const int gwave = (blockIdx.x * 256 + threadIdx.x) >> 6;
    const int lane = threadIdx.x & 63;
    const int e0 = gwave * 4;
#pragma unroll
    for (int i = 0; i < 4; ++i) {
        int e = e0 + i;
        if (e >= nnz) break;
        float v = vals[e];
        int r = orow[e];
        int c = gcol[e];
        float2 xv = *reinterpret_cast<const float2*>(&Xm[(size_t)c * D + lane * 2]);
        unsafeAtomicAdd(&outm[(size_t)r * D + lane * 2 + 0], v * xv.x);
        unsafeAtomicAdd(&outm[(size_t)r * D + lane * 2 + 1], v * xv.y);
    }
}

extern "C" void kernel_launch(void* const* d_in, const int* in_sizes, int n_in,
                              void* d_out, int out_size, void* d_ws, size_t ws_size,
                              hipStream_t stream) {
    const float* x      = (const float*)d_in[0];
    const float* y      = (const float*)d_in[1];
    const float* c      = (const float*)d_in[2];
    const float* b      = (const float*)d_in[3];
    const float* A_vals = (const float*)d_in[4];
    const int*   A_rows = (const int*)d_in[5];
    const int*   A_cols = (const int*)d_in[6];
    const float* Ukx_w  = (const float*)d_in[7];
    const float* Ukx_b  = (const float*)d_in[8];
    const float* Uky_w  = (const float*)d_in[9];
    const float* Uky_b  = (const float*)d_in[10];
    const float* tau    = (const float*)d_in[11];
    const float* Vky_w  = (const float*)d_in[12];
    const float* Vky_b  = (const float*)d_in[13];
    const float* Wkx_w  = (const float*)d_in[14];
    const float* Wkx_b  = (const float*)d_in[15];
    const float* Vkx_w  = (const float*)d_in[16];
    const float* Vkx_b  = (const float*)d_in[17];
    const float* sigma  = (const float*)d_in[18];

    const int N   = in_sizes[0] / D;        // 50000
    const int nnz = in_sizes[4];            // 1.6M
    const int nbk = (N + RB - 1) / RB;      // 782

    float* out_x = (float*)d_out;
    float* out_y = out_x + (size_t)N * D;

    const int gemm_grid = (N + 63) / 64;
    const int ggrid = (N + 3) / 4;

    // ws layout:
    //   region0 (transient union): recR|recC (2*nnz int2)  OR  tmp (N*D floats)
    //     - records are dead before zx-gemm writes tmp
    //   persistent: UkyT|UkxT|VkyT|WcT|bc | pairsR|pairsC (2*nnz int2) |
    //               cntR,cntC,goffR,goffC,gcurR,gcurC (6*nbk) | offR,lenR,offC,lenC (4*N)
    const size_t pool = (size_t)nnz;
    char* base = (char*)d_ws;
    float* tmp = (float*)base;
    int2* recR = (int2*)base;
    int2* recC = recR + pool;
    size_t region0 = (size_t)N * D * 4;
    if (2 * pool * 8 > region0) region0 = 2 * pool * 8;
    char* pers = base + region0;
    float* UkyT = (float*)pers;
    float* UkxT = UkyT + D * D;
    float* VkyT = UkxT + D * D;
    float* WcT  = VkyT + D * D;
    float* bc   = WcT + D * D;
    int2* pairsR = (int2*)(bc + D);
    int2* pairsC = pairsR + pool;
    int* cntR  = (int*)(pairsC + pool);
    int* cntC  = cntR + nbk;
    int* goffR = cntC + nbk;
    int* goffC = goffR + nbk;
    int* gcurR = goffC + nbk;
    int* gcurC = gcurR + nbk;
    int* offR  = gcurC + nbk;
    int* lenR  = offR + N;
    int* offC  = lenR + N;
    int* lenC  = offC + N;

    size_t need = region0 + (4 * (size_t)D * D + D) * 4 + 2 * pool * 8
                + (6 * (size_t)nbk + 4 * (size_t)N) * 4;

    setup_weights<<<4, 256, 0, stream>>>(Uky_w, Ukx_w, Vky_w, Vkx_w, Wkx_w,
                                         Vkx_b, Wkx_b, UkyT, UkxT, VkyT, WcT, bc);

    if (N < 65536 && nbk <= NBKMAX && ws_size >= need) {
        const int ce = (nnz + SCHUNKS - 1) / SCHUNKS;

        // ---- bucket build ----
        hipMemsetAsync(cntR, 0, 2 * (size_t)nbk * sizeof(int), stream);
        hist_buckets<<<SCHUNKS, 256, 0, stream>>>(A_rows, A_cols, cntR, cntC, nnz, nbk, ce);
        scan_buckets<<<2, 256, 0, stream>>>(cntR, cntC, goffR, gcurR, goffC, gcurC, nbk);
        scatter_buckets<<<SCHUNKS, 256, 0, stream>>>(A_rows, A_cols, A_vals,
                                                     gcurR, recR, gcurC, recC, nnz, nbk, ce);
        {
            dim3 g(nbk, 2);
            sort_buckets<<<g, 256, 0, stream>>>(recR, recC, goffR, cntR, goffC, cntC,
                                                pairsR, pairsC, offR, lenR, offC, lenC, N);
        }

        // uy = y @ Uky^T + b  -> staged in out_y
        gemm_v2<0><<<gemm_grid, 256, 0, stream>>>(y, UkyT, Uky_b, nullptr, nullptr, nullptr, out_y, N);
        // at_uy -> out_x   (grouped by A_cols; gather col = A_rows)
        spmm_pairs_v2<<<ggrid, 256, 0, stream>>>(pairsC, offC, lenC, out_y, out_x, N);
        // x_new -> out_x (in place)
        gemm_v2<1><<<gemm_grid, 256, 0, stream>>>(x, UkxT, Ukx_b, c, out_x, tau, out_x, N);
        // zx -> tmp   (recR/recC are dead now; tmp may overwrite them)
        gemm_v2<0><<<gemm_grid, 256, 0, stream>>>(out_x, WcT, bc, nullptr, nullptr, nullptr, tmp, N);
        // az -> out_y   (grouped by A_rows; gather col = A_cols)
        spmm_pairs_v2<<<ggrid, 256, 0, stream>>>(pairsR, offR, lenR, tmp, out_y, N);
        // y_new -> out_y (in place)
        gemm_v2<2><<<gemm_grid, 256, 0, stream>>>(y, VkyT, Vky_b, b, out_y, sigma, out_y, N);
    } else {
        // ---- atomic fallback ----
        const int spmm_grid = (nnz + 15) / 16;
        gemm_v2<0><<<gemm_grid, 256, 0, stream>>>(y, UkyT, Uky_b, nullptr, nullptr, nullptr, tmp, N);
        hipMemsetAsync(out_x, 0, (size_t)N * D * sizeof(float), stream);
        spmm_atomic<<<spmm_grid, 256, 0, stream>>>(A_vals, A_cols, A_rows, tmp, out_x, nnz);
        gemm_v2<1><<<gemm_grid, 256, 0, stream>>>(x, UkxT, Ukx_b, c, out_x, tau, out_x, N);
        gemm_v2<0><<<gemm_grid, 256, 0, stream>>>(out_x, WcT, bc, nullptr, nullptr, nullptr, tmp, N);
        hipMemsetAsync(out_y, 0, (size_t)N * D * sizeof(float), stream);
        spmm_atomic<<<spmm_grid, 256, 0, stream>>>(A_vals, A_rows, A_cols, tmp, out_y, nnz);
        gemm_v2<2><<<gemm_grid, 256, 0, stream>>>(y, VkyT, Vky_b, b, out_y, sigma, out_y, N);
    }
}

// Round 8
// 433.680 us; speedup vs baseline: 6.8155x; 1.1658x over previous
//
#include <hip/hip_runtime.h>

#define D 128
#define RB 64           // rows per bucket
#define NBKMAX 1024     // max buckets (N <= 65536)
#define CH 256          // edge chunks

// ---------------- setup: transpose weights + fold Wc = Vkx - 2*Wkx ----------------
__global__ __launch_bounds__(256) void setup_weights(
    const float* __restrict__ Uky, const float* __restrict__ Ukx,
    const float* __restrict__ Vky, const float* __restrict__ Vkx,
    const float* __restrict__ Wkx, const float* __restrict__ Vkx_b,
    const float* __restrict__ Wkx_b,
    float* __restrict__ UkyT, float* __restrict__ UkxT,
    float* __restrict__ VkyT, float* __restrict__ WcT, float* __restrict__ bc)
{
    const int m = blockIdx.x;
    const float* src = (m == 0) ? Uky : (m == 1) ? Ukx : (m == 2) ? Vky : nullptr;
    float* dst = (m == 0) ? UkyT : (m == 1) ? UkxT : (m == 2) ? VkyT : WcT;
    for (int i = threadIdx.x; i < D * D; i += 256) {
        int k = i >> 7, d = i & 127;
        float v;
        if (m == 3) v = Vkx[d * D + k] - 2.0f * Wkx[d * D + k];
        else        v = src[d * D + k];
        dst[i] = v;
    }
    if (m == 3 && threadIdx.x < D)
        bc[threadIdx.x] = Vkx_b[threadIdx.x] - 2.0f * Wkx_b[threadIdx.x];
}

// ---------------- fused GEMM v2 (pre-transposed W) ----------------
template <int EPI>
__global__ __launch_bounds__(256) void gemm_v2(
    const float* __restrict__ X, const float* __restrict__ WT,
    const float* __restrict__ bias, const float* __restrict__ colvec,
    const float* __restrict__ spout, const float* __restrict__ scal,
    float* __restrict__ out, int N)
{
    __shared__ float Xs[64][D + 4];
    __shared__ float Wt[64][D + 4];
    const int t = threadIdx.x;
    const int block_row = blockIdx.x * 64;

#pragma unroll
    for (int i = 0; i < 8; ++i) {
        int f = t + i * 256;
        int r = f >> 5;
        int k4 = (f & 31) << 2;
        float4 g = make_float4(0.f, 0.f, 0.f, 0.f);
        int row = block_row + r;
        if (row < N) g = *reinterpret_cast<const float4*>(&X[(size_t)row * D + k4]);
        *reinterpret_cast<float4*>(&Xs[r][k4]) = g;
    }

    const int cg = t & 15;
    const int rp = t >> 4;
    const int r0 = rp * 4;
    const int c0 = cg * 4, c1 = 64 + cg * 4;

    float acc[4][8] = {{0.f}};

    for (int kb = 0; kb < D; kb += 64) {
        __syncthreads();
#pragma unroll
        for (int i = 0; i < 8; ++i) {
            int f = t + i * 256;
            int kk = f >> 5;
            int d4 = (f & 31) << 2;
            float4 g = *reinterpret_cast<const float4*>(&WT[(size_t)(kb + kk) * D + d4]);
            *reinterpret_cast<float4*>(&Wt[kk][d4]) = g;
        }
        __syncthreads();
#pragma unroll 2
        for (int k4 = 0; k4 < 64; k4 += 4) {
            float4 xr[4];
#pragma unroll
            for (int j = 0; j < 4; ++j)
                xr[j] = *reinterpret_cast<const float4*>(&Xs[r0 + j][kb + k4]);
#pragma unroll
            for (int q = 0; q < 4; ++q) {
                const float4 w0 = *reinterpret_cast<const float4*>(&Wt[k4 + q][c0]);
                const float4 w1 = *reinterpret_cast<const float4*>(&Wt[k4 + q][c1]);
#pragma unroll
                for (int j = 0; j < 4; ++j) {
                    const float xv = (q == 0) ? xr[j].x : (q == 1) ? xr[j].y
                                   : (q == 2) ? xr[j].z : xr[j].w;
                    acc[j][0] += xv * w0.x; acc[j][1] += xv * w0.y;
                    acc[j][2] += xv * w0.z; acc[j][3] += xv * w0.w;
                    acc[j][4] += xv * w1.x; acc[j][5] += xv * w1.y;
                    acc[j][6] += xv * w1.z; acc[j][7] += xv * w1.w;
                }
            }
        }
    }

    const float sc = (EPI == 0) ? 0.f : scal[0];
    const float4 bias0 = *reinterpret_cast<const float4*>(&bias[c0]);
    const float4 bias1 = *reinterpret_cast<const float4*>(&bias[c1]);

#pragma unroll
    for (int j = 0; j < 4; ++j) {
        const int row = block_row + r0 + j;
        if (row >= N) continue;
        const float cv = (EPI == 0) ? 0.f : colvec[row];
#pragma unroll
        for (int h = 0; h < 2; ++h) {
            const int col = (h == 0) ? c0 : c1;
            const float4 bs = (h == 0) ? bias0 : bias1;
            float4 res;
            res.x = acc[j][h * 4 + 0] + bs.x;
            res.y = acc[j][h * 4 + 1] + bs.y;
            res.z = acc[j][h * 4 + 2] + bs.z;
            res.w = acc[j][h * 4 + 3] + bs.w;
            if (EPI == 1) {
                float4 sp = *reinterpret_cast<const float4*>(&spout[(size_t)row * D + col]);
                res.x = fmaxf(res.x - sc * (cv - sp.x), 0.f);
                res.y = fmaxf(res.y - sc * (cv - sp.y), 0.f);
                res.z = fmaxf(res.z - sc * (cv - sp.z), 0.f);
                res.w = fmaxf(res.w - sc * (cv - sp.w), 0.f);
            } else if (EPI == 2) {
                float4 sp = *reinterpret_cast<const float4*>(&spout[(size_t)row * D + col]);
                res.x = fmaxf(res.x - sc * (cv + sp.x), 0.f);
                res.y = fmaxf(res.y - sc * (cv + sp.y), 0.f);
                res.z = fmaxf(res.z - sc * (cv + sp.z), 0.f);
                res.w = fmaxf(res.w - sc * (cv + sp.w), 0.f);
            }
            *reinterpret_cast<float4*>(&out[(size_t)row * D + col]) = res;
        }
    }
}

// ---------------- K1: per-chunk bucket histogram -> h[g][chunk][b] ----------------
__global__ __launch_bounds__(256) void hist_chunks(
    const int* __restrict__ rows, const int* __restrict__ cols,
    int* __restrict__ hR, int* __restrict__ hC, int nnz, int nbk, int ce)
{
    __shared__ int lh[NBKMAX];
    const int chunk = blockIdx.x;
    const bool isC = blockIdx.y;
    const int* idx = isC ? cols : rows;
    int* hout = (isC ? hC : hR) + (size_t)chunk * nbk;
    for (int i = threadIdx.x; i < nbk; i += 256) lh[i] = 0;
    __syncthreads();
    const int e0 = chunk * ce, e1 = min(nnz, e0 + ce);
    for (int e = e0 + threadIdx.x; e < e1; e += 256)
        atomicAdd(&lh[idx[e] >> 6], 1);
    __syncthreads();
    for (int i = threadIdx.x; i < nbk; i += 256) hout[i] = lh[i];
}

// ---------------- K2: bucket totals cnt[b] = sum_c h[c][b] ----------------
__global__ __launch_bounds__(256) void bucket_tot(
    const int* __restrict__ hR, const int* __restrict__ hC,
    int* __restrict__ cntR, int* __restrict__ cntC, int nbk)
{
    const int b = blockIdx.x;
    const bool isC = blockIdx.y;
    const int* h = (isC ? hC : hR);
    __shared__ int s[256];
    int v = h[(size_t)threadIdx.x * nbk + b];
    s[threadIdx.x] = v;
    __syncthreads();
#pragma unroll
    for (int d = 128; d > 0; d >>= 1) {
        if (threadIdx.x < d) s[threadIdx.x] += s[threadIdx.x + d];
        __syncthreads();
    }
    if (threadIdx.x == 0) (isC ? cntC : cntR)[b] = s[0];
}

// ---------------- K3: bucket scan -> goff ----------------
__global__ __launch_bounds__(256) void scan_buckets(
    const int* __restrict__ cntR, const int* __restrict__ cntC,
    int* __restrict__ goffR, int* __restrict__ goffC, int nbk)
{
    const int* cnt = blockIdx.x ? cntC : cntR;
    int* goff = blockIdx.x ? goffC : goffR;
    __shared__ int s[256];
    const int t = threadIdx.x;
    const int base = t * 4;
    int loc[4]; int sum = 0;
#pragma unroll
    for (int u = 0; u < 4; ++u) {
        int idx = base + u;
        int v = (idx < nbk) ? cnt[idx] : 0;
        loc[u] = sum; sum += v;
    }
    s[t] = sum;
    __syncthreads();
#pragma unroll
    for (int d = 1; d < 256; d <<= 1) {
        int tv = (t >= d) ? s[t - d] : 0;
        __syncthreads();
        s[t] += tv;
        __syncthreads();
    }
    int excl = s[t] - sum;
#pragma unroll
    for (int u = 0; u < 4; ++u) {
        int idx = base + u;
        if (idx < nbk) goff[idx] = excl + loc[u];
    }
}

// ---------------- K4: run starts (in-place h -> rs) ----------------
// rs[c][b] = goff[b] + prefix_{c'<c} h[c'][b]
__global__ __launch_bounds__(256) void runstarts(
    int* __restrict__ hR, int* __restrict__ hC,
    const int* __restrict__ goffR, const int* __restrict__ goffC, int nbk)
{
    const int b = blockIdx.x;
    const bool isC = blockIdx.y;
    int* h = (isC ? hC : hR);
    const int g0 = (isC ? goffC : goffR)[b];
    __shared__ int s[256];
    const int t = threadIdx.x;
    int v = h[(size_t)t * nbk + b];
    s[t] = v;
    __syncthreads();
#pragma unroll
    for (int d = 1; d < 256; d <<= 1) {
        int tv = (t >= d) ? s[t - d] : 0;
        __syncthreads();
        s[t] += tv;
        __syncthreads();
    }
    h[(size_t)t * nbk + b] = g0 + s[t] - v;   // exclusive prefix + base
}

// ---------------- K5: scatter with LDS cursors only (no global atomics) -----------
// record = { (dest%64)<<16 | gather_col , val_bits }  (needs N < 65536)
__global__ __launch_bounds__(256) void scatter_chunks(
    const int* __restrict__ rows, const int* __restrict__ cols,
    const float* __restrict__ vals,
    const int* __restrict__ rsR, int2* __restrict__ recR,
    const int* __restrict__ rsC, int2* __restrict__ recC,
    int nnz, int nbk, int ce)
{
    __shared__ int lrsR[NBKMAX], lcurR[NBKMAX];
    __shared__ int lrsC[NBKMAX], lcurC[NBKMAX];
    const int chunk = blockIdx.x;
    for (int i = threadIdx.x; i < nbk; i += 256) {
        lrsR[i] = rsR[(size_t)chunk * nbk + i]; lcurR[i] = 0;
        lrsC[i] = rsC[(size_t)chunk * nbk + i]; lcurC[i] = 0;
    }
    __syncthreads();
    const int e0 = chunk * ce, e1 = min(nnz, e0 + ce);
    for (int e = e0 + threadIdx.x; e < e1; e += 256) {
        int r = rows[e], c = cols[e];
        int vb = __float_as_int(vals[e]);
        int bR = r >> 6, bC = c >> 6;
        int pR = lrsR[bR] + atomicAdd(&lcurR[bR], 1);
        recR[pR] = make_int2(((r & 63) << 16) | c, vb);
        int pC = lrsC[bC] + atomicAdd(&lcurC[bC], 1);
        recC[pC] = make_int2(((c & 63) << 16) | r, vb);
    }
}

// ---------------- per-bucket row sort: records -> row-contiguous pairs ------------
__global__ __launch_bounds__(256) void sort_buckets(
    const int2* __restrict__ recR, const int2* __restrict__ recC,
    const int* __restrict__ goffR, const int* __restrict__ cntR,
    const int* __restrict__ goffC, const int* __restrict__ cntC,
    int2* __restrict__ pairsR, int2* __restrict__ pairsC,
    int* __restrict__ offR, int* __restrict__ lenR,
    int* __restrict__ offC, int* __restrict__ lenC, int N)
{
    const bool isC = blockIdx.y;
    const int b = blockIdx.x;
    const int2* rec = isC ? recC : recR;
    int2* pairs = isC ? pairsC : pairsR;
    int* off = isC ? offC : offR;
    int* len = isC ? lenC : lenR;
    const int s = (isC ? goffC : goffR)[b];
    const int L = (isC ? cntC : cntR)[b];
    const int t = threadIdx.x;

    __shared__ int lcnt[RB], lpos[RB], lcur[RB];
    if (t < RB) lcnt[t] = 0;
    __syncthreads();
    for (int i = t; i < L; i += 256)
        atomicAdd(&lcnt[rec[s + i].x >> 16], 1);
    __syncthreads();
    if (t == 0) {
        int run = 0;
#pragma unroll
        for (int r = 0; r < RB; ++r) { lpos[r] = run; run += lcnt[r]; }
    }
    __syncthreads();
    if (t < RB) {
        int row = b * RB + t;
        if (row < N) { off[row] = s + lpos[t]; len[row] = lcnt[t]; }
        lcur[t] = 0;
    }
    __syncthreads();
    for (int i = t; i < L; i += 256) {
        int2 pr = rec[s + i];
        int r = pr.x >> 16;
        int p = lpos[r] + atomicAdd(&lcur[r], 1);
        pairs[s + p] = make_int2(pr.x & 0xFFFF, pr.y);
    }
}

// ---------------- pairs-gather SpMM (wave-per-row) ----------------
__global__ __launch_bounds__(256) void spmm_pairs_v2(
    const int2* __restrict__ pairs, const int* __restrict__ off,
    const int* __restrict__ len, const float* __restrict__ X,
    float* __restrict__ out, int N)
{
    const int row = (blockIdx.x * 256 + threadIdx.x) >> 6;
    if (row >= N) return;
    const int lane = threadIdx.x & 63;
    const int half = lane >> 5;
    const int cq = (lane & 31) << 2;
    const int s = off[row];
    const int L = len[row];

    float4 a0 = make_float4(0.f, 0.f, 0.f, 0.f);
    float4 a1 = make_float4(0.f, 0.f, 0.f, 0.f);
    float4 a2 = make_float4(0.f, 0.f, 0.f, 0.f);
    float4 a3 = make_float4(0.f, 0.f, 0.f, 0.f);

    int i = 0;
    for (; i + 7 < L; i += 8) {
        int2 p0 = pairs[s + i + 0 + half];
        int2 p1 = pairs[s + i + 2 + half];
        int2 p2 = pairs[s + i + 4 + half];
        int2 p3 = pairs[s + i + 6 + half];
        float4 x0 = *reinterpret_cast<const float4*>(&X[(size_t)p0.x * D + cq]);
        float4 x1 = *reinterpret_cast<const float4*>(&X[(size_t)p1.x * D + cq]);
        float4 x2 = *reinterpret_cast<const float4*>(&X[(size_t)p2.x * D + cq]);
        float4 x3 = *reinterpret_cast<const float4*>(&X[(size_t)p3.x * D + cq]);
        float v0 = __int_as_float(p0.y), v1 = __int_as_float(p1.y);
        float v2 = __int_as_float(p2.y), v3 = __int_as_float(p3.y);
        a0.x += v0 * x0.x; a0.y += v0 * x0.y; a0.z += v0 * x0.z; a0.w += v0 * x0.w;
        a1.x += v1 * x1.x; a1.y += v1 * x1.y; a1.z += v1 * x1.z; a1.w += v1 * x1.w;
        a2.x += v2 * x2.x; a2.y += v2 * x2.y; a2.z += v2 * x2.z; a2.w += v2 * x2.w;
        a3.x += v3 * x3.x; a3.y += v3 * x3.y; a3.z += v3 * x3.z; a3.w += v3 * x3.w;
    }
    for (; i < L; i += 2) {
        int e = i + half;
        int2 p = (e < L) ? pairs[s + e] : make_int2(0, 0);
        float v = __int_as_float(p.y);
        float4 xv = *reinterpret_cast<const float4*>(&X[(size_t)p.x * D + cq]);
        a0.x += v * xv.x; a0.y += v * xv.y; a0.z += v * xv.z; a0.w += v * xv.w;
    }

    float4 A;
    A.x = (a0.x + a1.x) + (a2.x + a3.x);
    A.y = (a0.y + a1.y) + (a2.y + a3.y);
    A.z = (a0.z + a1.z) + (a2.z + a3.z);
    A.w = (a0.w + a1.w) + (a2.w + a3.w);
    A.x += __shfl_xor(A.x, 32);
    A.y += __shfl_xor(A.y, 32);
    A.z += __shfl_xor(A.z, 32);
    A.w += __shfl_xor(A.w, 32);
    if (half == 0)
        *reinterpret_cast<float4*>(&out[(size_t)row * D + cq]) = A;
}

// ---------------- atomic fallback ----------------
__global__ __launch_bounds__(256) void spmm_atomic(
    const float* __restrict__ vals, const int* __restrict__ orow,
    const int* __restrict__ gcol, const float* __restrict__ Xm,
    float* __restrict__ outm, int nnz)
{
    const int gwave = (blockIdx.x * 256 + threadIdx.x) >> 6;
    const int lane = threadIdx.x & 63;
    const int e0 = gwave * 4;
#pragma unroll
    for (int i = 0; i < 4; ++i) {
        int e = e0 + i;
        if (e >= nnz) break;
        float v = vals[e];
        int r = orow[e];
        int c = gcol[e];
        float2 xv = *reinterpret_cast<const float2*>(&Xm[(size_t)c * D + lane * 2]);
        unsafeAtomicAdd(&outm[(size_t)r * D + lane * 2 + 0], v * xv.x);
        unsafeAtomicAdd(&outm[(size_t)r * D + lane * 2 + 1], v * xv.y);
    }
}

extern "C" void kernel_launch(void* const* d_in, const int* in_sizes, int n_in,
                              void* d_out, int out_size, void* d_ws, size_t ws_size,
                              hipStream_t stream) {
    const float* x      = (const float*)d_in[0];
    const float* y      = (const float*)d_in[1];
    const float* c      = (const float*)d_in[2];
    const float* b      = (const float*)d_in[3];
    const float* A_vals = (const float*)d_in[4];
    const int*   A_rows = (const int*)d_in[5];
    const int*   A_cols = (const int*)d_in[6];
    const float* Ukx_w  = (const float*)d_in[7];
    const float* Ukx_b  = (const float*)d_in[8];
    const float* Uky_w  = (const float*)d_in[9];
    const float* Uky_b  = (const float*)d_in[10];
    const float* tau    = (const float*)d_in[11];
    const float* Vky_w  = (const float*)d_in[12];
    const float* Vky_b  = (const float*)d_in[13];
    const float* Wkx_w  = (const float*)d_in[14];
    const float* Wkx_b  = (const float*)d_in[15];
    const float* Vkx_w  = (const float*)d_in[16];
    const float* Vkx_b  = (const float*)d_in[17];
    const float* sigma  = (const float*)d_in[18];

    const int N   = in_sizes[0] / D;        // 50000
    const int nnz = in_sizes[4];            // 1.6M
    const int nbk = (N + RB - 1) / RB;      // 782

    float* out_x = (float*)d_out;
    float* out_y = out_x + (size_t)N * D;

    const int gemm_grid = (N + 63) / 64;
    const int ggrid = (N + 3) / 4;

    // ws layout:
    //   region0 (transient union): recR|recC (2*nnz int2)  OR  tmp (N*D floats)
    //   persistent: UkyT|UkxT|VkyT|WcT|bc | pairsR|pairsC (2*nnz int2) |
    //               cntR,cntC,goffR,goffC (4*nbk) | offR,lenR,offC,lenC (4*N)
    //   h/rs (2*CH*nbk ints) ALIASES the head of pairsR (dead before sort writes)
    const size_t pool = (size_t)nnz;
    char* base = (char*)d_ws;
    float* tmp = (float*)base;
    int2* recR = (int2*)base;
    int2* recC = recR + pool;
    size_t region0 = (size_t)N * D * 4;
    if (2 * pool * 8 > region0) region0 = 2 * pool * 8;
    char* pers = base + region0;
    float* UkyT = (float*)pers;
    float* UkxT = UkyT + D * D;
    float* VkyT = UkxT + D * D;
    float* WcT  = VkyT + D * D;
    float* bc   = WcT + D * D;
    int2* pairsR = (int2*)(bc + D);
    int2* pairsC = pairsR + pool;
    int* cntR  = (int*)(pairsC + pool);
    int* cntC  = cntR + nbk;
    int* goffR = cntC + nbk;
    int* goffC = goffR + nbk;
    int* offR  = goffC + nbk;
    int* lenR  = offR + N;
    int* offC  = lenR + N;
    int* lenC  = offC + N;
    // h/rs alias pairsR head: 2*CH*nbk ints (<= 2 MB) fits in pairsR (12.8 MB)
    int* hR = (int*)pairsR;
    int* hC = hR + (size_t)CH * nbk;

    size_t need = region0 + (4 * (size_t)D * D + D) * 4 + 2 * pool * 8
                + (4 * (size_t)nbk + 4 * (size_t)N) * 4;
    bool h_fits = (size_t)2 * CH * nbk * 4 <= pool * 8;

    setup_weights<<<4, 256, 0, stream>>>(Uky_w, Ukx_w, Vky_w, Vkx_w, Wkx_w,
                                         Vkx_b, Wkx_b, UkyT, UkxT, VkyT, WcT, bc);

    if (N < 65536 && nbk <= NBKMAX && ws_size >= need && h_fits) {
        const int ce = (nnz + CH - 1) / CH;

        // ---- radix-style build (no global atomics) ----
        {
            dim3 g1(CH, 2);
            hist_chunks<<<g1, 256, 0, stream>>>(A_rows, A_cols, hR, hC, nnz, nbk, ce);
            dim3 g2(nbk, 2);
            bucket_tot<<<g2, 256, 0, stream>>>(hR, hC, cntR, cntC, nbk);
            scan_buckets<<<2, 256, 0, stream>>>(cntR, cntC, goffR, goffC, nbk);
            runstarts<<<g2, 256, 0, stream>>>(hR, hC, goffR, goffC, nbk);
            scatter_chunks<<<CH, 256, 0, stream>>>(A_rows, A_cols, A_vals,
                                                   hR, recR, hC, recC, nnz, nbk, ce);
            sort_buckets<<<g2, 256, 0, stream>>>(recR, recC, goffR, cntR, goffC, cntC,
                                                 pairsR, pairsC, offR, lenR, offC, lenC, N);
        }

        // uy = y @ Uky^T + b  -> staged in out_y
        gemm_v2<0><<<gemm_grid, 256, 0, stream>>>(y, UkyT, Uky_b, nullptr, nullptr, nullptr, out_y, N);
        // at_uy -> out_x   (grouped by A_cols; gather col = A_rows)
        spmm_pairs_v2<<<ggrid, 256, 0, stream>>>(pairsC, offC, lenC, out_y, out_x, N);
        // x_new -> out_x (in place)
        gemm_v2<1><<<gemm_grid, 256, 0, stream>>>(x, UkxT, Ukx_b, c, out_x, tau, out_x, N);
        // zx -> tmp   (recR/recC are dead now)
        gemm_v2<0><<<gemm_grid, 256, 0, stream>>>(out_x, WcT, bc, nullptr, nullptr, nullptr, tmp, N);
        // az -> out_y   (grouped by A_rows; gather col = A_cols)
        spmm_pairs_v2<<<ggrid, 256, 0, stream>>>(pairsR, offR, lenR, tmp, out_y, N);
        // y_new -> out_y (in place)
        gemm_v2<2><<<gemm_grid, 256, 0, stream>>>(y, VkyT, Vky_b, b, out_y, sigma, out_y, N);
    } else {
        // ---- atomic fallback ----
        const int spmm_grid = (nnz + 15) / 16;
        gemm_v2<0><<<gemm_grid, 256, 0, stream>>>(y, UkyT, Uky_b, nullptr, nullptr, nullptr, tmp, N);
        hipMemsetAsync(out_x, 0, (size_t)N * D * sizeof(float), stream);
        spmm_atomic<<<spmm_grid, 256, 0, stream>>>(A_vals, A_cols, A_rows, tmp, out_x, nnz);
        gemm_v2<1><<<gemm_grid, 256, 0, stream>>>(x, UkxT, Ukx_b, c, out_x, tau, out_x, N);
        gemm_v2<0><<<gemm_grid, 256, 0, stream>>>(out_x, WcT, bc, nullptr, nullptr, nullptr, tmp, N);
        hipMemsetAsync(out_y, 0, (size_t)N * D * sizeof(float), stream);
        spmm_atomic<<<spmm_grid, 256, 0, stream>>>(A_vals, A_rows, A_cols, tmp, out_y, nnz);
        gemm_v2<2><<<gemm_grid, 256, 0, stream>>>(y, VkyT, Vky_b, b, out_y, sigma, out_y, N);
    }
}

// Round 9
// 330.034 us; speedup vs baseline: 8.9559x; 1.3140x over previous
//
#include <hip/hip_runtime.h>

#define D 128
#define RB 64           // rows per bucket
#define NBKMAX 1024     // max buckets (N <= 65536)
#define CH 256          // edge chunks

__device__ __forceinline__ unsigned short bf16r(float f) {
    unsigned b = __float_as_uint(f);
    return (unsigned short)((b + 0x7FFFu + ((b >> 16) & 1u)) >> 16);
}

// ---------------- setup: transpose weights + fold Wc = Vkx - 2*Wkx ----------------
__global__ __launch_bounds__(256) void setup_weights(
    const float* __restrict__ Uky, const float* __restrict__ Ukx,
    const float* __restrict__ Vky, const float* __restrict__ Vkx,
    const float* __restrict__ Wkx, const float* __restrict__ Vkx_b,
    const float* __restrict__ Wkx_b,
    float* __restrict__ UkyT, float* __restrict__ UkxT,
    float* __restrict__ VkyT, float* __restrict__ WcT, float* __restrict__ bc)
{
    const int m = blockIdx.x;
    const float* src = (m == 0) ? Uky : (m == 1) ? Ukx : (m == 2) ? Vky : nullptr;
    float* dst = (m == 0) ? UkyT : (m == 1) ? UkxT : (m == 2) ? VkyT : WcT;
    for (int i = threadIdx.x; i < D * D; i += 256) {
        int k = i >> 7, d = i & 127;
        float v;
        if (m == 3) v = Vkx[d * D + k] - 2.0f * Wkx[d * D + k];
        else        v = src[d * D + k];
        dst[i] = v;
    }
    if (m == 3 && threadIdx.x < D)
        bc[threadIdx.x] = Vkx_b[threadIdx.x] - 2.0f * Wkx_b[threadIdx.x];
}

// ---------------- fused GEMM v2 (pre-transposed W) ----------------
// OB16=1: write bf16 (rounded) instead of fp32  (used for spmm gather operands)
template <int EPI, int OB16>
__global__ __launch_bounds__(256) void gemm_v2(
    const float* __restrict__ X, const float* __restrict__ WT,
    const float* __restrict__ bias, const float* __restrict__ colvec,
    const float* __restrict__ spout, const float* __restrict__ scal,
    float* __restrict__ out, int N)
{
    __shared__ float Xs[64][D + 4];
    __shared__ float Wt[64][D + 4];
    const int t = threadIdx.x;
    const int block_row = blockIdx.x * 64;

#pragma unroll
    for (int i = 0; i < 8; ++i) {
        int f = t + i * 256;
        int r = f >> 5;
        int k4 = (f & 31) << 2;
        float4 g = make_float4(0.f, 0.f, 0.f, 0.f);
        int row = block_row + r;
        if (row < N) g = *reinterpret_cast<const float4*>(&X[(size_t)row * D + k4]);
        *reinterpret_cast<float4*>(&Xs[r][k4]) = g;
    }

    const int cg = t & 15;
    const int rp = t >> 4;
    const int r0 = rp * 4;
    const int c0 = cg * 4, c1 = 64 + cg * 4;

    float acc[4][8] = {{0.f}};

    for (int kb = 0; kb < D; kb += 64) {
        __syncthreads();
#pragma unroll
        for (int i = 0; i < 8; ++i) {
            int f = t + i * 256;
            int kk = f >> 5;
            int d4 = (f & 31) << 2;
            float4 g = *reinterpret_cast<const float4*>(&WT[(size_t)(kb + kk) * D + d4]);
            *reinterpret_cast<float4*>(&Wt[kk][d4]) = g;
        }
        __syncthreads();
#pragma unroll 2
        for (int k4 = 0; k4 < 64; k4 += 4) {
            float4 xr[4];
#pragma unroll
            for (int j = 0; j < 4; ++j)
                xr[j] = *reinterpret_cast<const float4*>(&Xs[r0 + j][kb + k4]);
#pragma unroll
            for (int q = 0; q < 4; ++q) {
                const float4 w0 = *reinterpret_cast<const float4*>(&Wt[k4 + q][c0]);
                const float4 w1 = *reinterpret_cast<const float4*>(&Wt[k4 + q][c1]);
#pragma unroll
                for (int j = 0; j < 4; ++j) {
                    const float xv = (q == 0) ? xr[j].x : (q == 1) ? xr[j].y
                                   : (q == 2) ? xr[j].z : xr[j].w;
                    acc[j][0] += xv * w0.x; acc[j][1] += xv * w0.y;
                    acc[j][2] += xv * w0.z; acc[j][3] += xv * w0.w;
                    acc[j][4] += xv * w1.x; acc[j][5] += xv * w1.y;
                    acc[j][6] += xv * w1.z; acc[j][7] += xv * w1.w;
                }
            }
        }
    }

    const float sc = (EPI == 0) ? 0.f : scal[0];
    const float4 bias0 = *reinterpret_cast<const float4*>(&bias[c0]);
    const float4 bias1 = *reinterpret_cast<const float4*>(&bias[c1]);

#pragma unroll
    for (int j = 0; j < 4; ++j) {
        const int row = block_row + r0 + j;
        if (row >= N) continue;
        const float cv = (EPI == 0) ? 0.f : colvec[row];
#pragma unroll
        for (int h = 0; h < 2; ++h) {
            const int col = (h == 0) ? c0 : c1;
            const float4 bs = (h == 0) ? bias0 : bias1;
            float4 res;
            res.x = acc[j][h * 4 + 0] + bs.x;
            res.y = acc[j][h * 4 + 1] + bs.y;
            res.z = acc[j][h * 4 + 2] + bs.z;
            res.w = acc[j][h * 4 + 3] + bs.w;
            if (EPI == 1) {
                float4 sp = *reinterpret_cast<const float4*>(&spout[(size_t)row * D + col]);
                res.x = fmaxf(res.x - sc * (cv - sp.x), 0.f);
                res.y = fmaxf(res.y - sc * (cv - sp.y), 0.f);
                res.z = fmaxf(res.z - sc * (cv - sp.z), 0.f);
                res.w = fmaxf(res.w - sc * (cv - sp.w), 0.f);
            } else if (EPI == 2) {
                float4 sp = *reinterpret_cast<const float4*>(&spout[(size_t)row * D + col]);
                res.x = fmaxf(res.x - sc * (cv + sp.x), 0.f);
                res.y = fmaxf(res.y - sc * (cv + sp.y), 0.f);
                res.z = fmaxf(res.z - sc * (cv + sp.z), 0.f);
                res.w = fmaxf(res.w - sc * (cv + sp.w), 0.f);
            }
            if (OB16) {
                unsigned short* ob = (unsigned short*)out;
                ushort4 r16;
                r16.x = bf16r(res.x); r16.y = bf16r(res.y);
                r16.z = bf16r(res.z); r16.w = bf16r(res.w);
                *reinterpret_cast<ushort4*>(&ob[(size_t)row * D + col]) = r16;
            } else {
                *reinterpret_cast<float4*>(&out[(size_t)row * D + col]) = res;
            }
        }
    }
}

// ---------------- K1: per-chunk bucket histogram -> h[g][chunk][b] ----------------
__global__ __launch_bounds__(256) void hist_chunks(
    const int* __restrict__ rows, const int* __restrict__ cols,
    int* __restrict__ hR, int* __restrict__ hC, int nnz, int nbk, int ce)
{
    __shared__ int lh[NBKMAX];
    const int chunk = blockIdx.x;
    const bool isC = blockIdx.y;
    const int* idx = isC ? cols : rows;
    int* hout = (isC ? hC : hR) + (size_t)chunk * nbk;
    for (int i = threadIdx.x; i < nbk; i += 256) lh[i] = 0;
    __syncthreads();
    const int e0 = chunk * ce, e1 = min(nnz, e0 + ce);
    for (int e = e0 + threadIdx.x; e < e1; e += 256)
        atomicAdd(&lh[idx[e] >> 6], 1);
    __syncthreads();
    for (int i = threadIdx.x; i < nbk; i += 256) hout[i] = lh[i];
}

// ---------------- K2: bucket totals ----------------
__global__ __launch_bounds__(256) void bucket_tot(
    const int* __restrict__ hR, const int* __restrict__ hC,
    int* __restrict__ cntR, int* __restrict__ cntC, int nbk)
{
    const int b = blockIdx.x;
    const bool isC = blockIdx.y;
    const int* h = (isC ? hC : hR);
    __shared__ int s[256];
    int v = h[(size_t)threadIdx.x * nbk + b];
    s[threadIdx.x] = v;
    __syncthreads();
#pragma unroll
    for (int d = 128; d > 0; d >>= 1) {
        if (threadIdx.x < d) s[threadIdx.x] += s[threadIdx.x + d];
        __syncthreads();
    }
    if (threadIdx.x == 0) (isC ? cntC : cntR)[b] = s[0];
}

// ---------------- K3: bucket scan -> goff ----------------
__global__ __launch_bounds__(256) void scan_buckets(
    const int* __restrict__ cntR, const int* __restrict__ cntC,
    int* __restrict__ goffR, int* __restrict__ goffC, int nbk)
{
    const int* cnt = blockIdx.x ? cntC : cntR;
    int* goff = blockIdx.x ? goffC : goffR;
    __shared__ int s[256];
    const int t = threadIdx.x;
    const int base = t * 4;
    int loc[4]; int sum = 0;
#pragma unroll
    for (int u = 0; u < 4; ++u) {
        int idx = base + u;
        int v = (idx < nbk) ? cnt[idx] : 0;
        loc[u] = sum; sum += v;
    }
    s[t] = sum;
    __syncthreads();
#pragma unroll
    for (int d = 1; d < 256; d <<= 1) {
        int tv = (t >= d) ? s[t - d] : 0;
        __syncthreads();
        s[t] += tv;
        __syncthreads();
    }
    int excl = s[t] - sum;
#pragma unroll
    for (int u = 0; u < 4; ++u) {
        int idx = base + u;
        if (idx < nbk) goff[idx] = excl + loc[u];
    }
}

// ---------------- K4: run starts (in-place h -> rs) ----------------
__global__ __launch_bounds__(256) void runstarts(
    int* __restrict__ hR, int* __restrict__ hC,
    const int* __restrict__ goffR, const int* __restrict__ goffC, int nbk)
{
    const int b = blockIdx.x;
    const bool isC = blockIdx.y;
    int* h = (isC ? hC : hR);
    const int g0 = (isC ? goffC : goffR)[b];
    __shared__ int s[256];
    const int t = threadIdx.x;
    int v = h[(size_t)t * nbk + b];
    s[t] = v;
    __syncthreads();
#pragma unroll
    for (int d = 1; d < 256; d <<= 1) {
        int tv = (t >= d) ? s[t - d] : 0;
        __syncthreads();
        s[t] += tv;
        __syncthreads();
    }
    h[(size_t)t * nbk + b] = g0 + s[t] - v;
}

// ---------------- K5: scatter with LDS cursors only ----------------
// record = { (dest%64)<<16 | gather_col , val_bits }  (needs N < 65536)
__global__ __launch_bounds__(256) void scatter_chunks(
    const int* __restrict__ rows, const int* __restrict__ cols,
    const float* __restrict__ vals,
    const int* __restrict__ rsR, int2* __restrict__ recR,
    const int* __restrict__ rsC, int2* __restrict__ recC,
    int nnz, int nbk, int ce)
{
    __shared__ int lrsR[NBKMAX], lcurR[NBKMAX];
    __shared__ int lrsC[NBKMAX], lcurC[NBKMAX];
    const int chunk = blockIdx.x;
    for (int i = threadIdx.x; i < nbk; i += 256) {
        lrsR[i] = rsR[(size_t)chunk * nbk + i]; lcurR[i] = 0;
        lrsC[i] = rsC[(size_t)chunk * nbk + i]; lcurC[i] = 0;
    }
    __syncthreads();
    const int e0 = chunk * ce, e1 = min(nnz, e0 + ce);
    for (int e = e0 + threadIdx.x; e < e1; e += 256) {
        int r = rows[e], c = cols[e];
        int vb = __float_as_int(vals[e]);
        int bR = r >> 6, bC = c >> 6;
        int pR = lrsR[bR] + atomicAdd(&lcurR[bR], 1);
        recR[pR] = make_int2(((r & 63) << 16) | c, vb);
        int pC = lrsC[bC] + atomicAdd(&lcurC[bC], 1);
        recC[pC] = make_int2(((c & 63) << 16) | r, vb);
    }
}

// ---------------- per-bucket row sort: records -> row-contiguous PACKED pairs -----
// pair = (bf16(val) << 16) | gather_col
__global__ __launch_bounds__(256) void sort_buckets(
    const int2* __restrict__ recR, const int2* __restrict__ recC,
    const int* __restrict__ goffR, const int* __restrict__ cntR,
    const int* __restrict__ goffC, const int* __restrict__ cntC,
    unsigned* __restrict__ pairsR, unsigned* __restrict__ pairsC,
    int* __restrict__ offR, int* __restrict__ lenR,
    int* __restrict__ offC, int* __restrict__ lenC, int N)
{
    const bool isC = blockIdx.y;
    const int b = blockIdx.x;
    const int2* rec = isC ? recC : recR;
    unsigned* pairs = isC ? pairsC : pairsR;
    int* off = isC ? offC : offR;
    int* len = isC ? lenC : lenR;
    const int s = (isC ? goffC : goffR)[b];
    const int L = (isC ? cntC : cntR)[b];
    const int t = threadIdx.x;

    __shared__ int lcnt[RB], lpos[RB], lcur[RB];
    if (t < RB) lcnt[t] = 0;
    __syncthreads();
    for (int i = t; i < L; i += 256)
        atomicAdd(&lcnt[rec[s + i].x >> 16], 1);
    __syncthreads();
    if (t == 0) {
        int run = 0;
#pragma unroll
        for (int r = 0; r < RB; ++r) { lpos[r] = run; run += lcnt[r]; }
    }
    __syncthreads();
    if (t < RB) {
        int row = b * RB + t;
        if (row < N) { off[row] = s + lpos[t]; len[row] = lcnt[t]; }
        lcur[t] = 0;
    }
    __syncthreads();
    for (int i = t; i < L; i += 256) {
        int2 pr = rec[s + i];
        int r = pr.x >> 16;
        int p = lpos[r] + atomicAdd(&lcur[r], 1);
        unsigned vb = (unsigned)pr.y;
        unsigned v16 = (vb + 0x7FFFu + ((vb >> 16) & 1u)) >> 16;
        pairs[s + p] = (v16 << 16) | (unsigned)(pr.x & 0xFFFF);
    }
}

// ---------------- pairs-gather SpMM v3: bf16 X, packed 4B pairs ----------------
__global__ __launch_bounds__(256) void spmm_pairs_v3(
    const unsigned* __restrict__ pairs, const int* __restrict__ off,
    const int* __restrict__ len, const unsigned short* __restrict__ Xb,
    float* __restrict__ out, int N)
{
    const int row = (blockIdx.x * 256 + threadIdx.x) >> 6;
    if (row >= N) return;
    const int lane = threadIdx.x & 63;
    const int half = lane >> 5;
    const int cq = (lane & 31) << 2;      // 4 bf16 cols per lane
    const int s = off[row];
    const int L = len[row];

    float4 a0 = make_float4(0.f, 0.f, 0.f, 0.f);
    float4 a1 = make_float4(0.f, 0.f, 0.f, 0.f);
    float4 a2 = make_float4(0.f, 0.f, 0.f, 0.f);
    float4 a3 = make_float4(0.f, 0.f, 0.f, 0.f);

#define BF(u) __uint_as_float((unsigned)(u) << 16)
    int i = 0;
    for (; i + 7 < L; i += 8) {
        unsigned p0 = pairs[s + i + 0 + half];
        unsigned p1 = pairs[s + i + 2 + half];
        unsigned p2 = pairs[s + i + 4 + half];
        unsigned p3 = pairs[s + i + 6 + half];
        ushort4 x0 = *reinterpret_cast<const ushort4*>(&Xb[(size_t)(p0 & 0xFFFFu) * D + cq]);
        ushort4 x1 = *reinterpret_cast<const ushort4*>(&Xb[(size_t)(p1 & 0xFFFFu) * D + cq]);
        ushort4 x2 = *reinterpret_cast<const ushort4*>(&Xb[(size_t)(p2 & 0xFFFFu) * D + cq]);
        ushort4 x3 = *reinterpret_cast<const ushort4*>(&Xb[(size_t)(p3 & 0xFFFFu) * D + cq]);
        float v0 = __uint_as_float(p0 & 0xFFFF0000u);
        float v1 = __uint_as_float(p1 & 0xFFFF0000u);
        float v2 = __uint_as_float(p2 & 0xFFFF0000u);
        float v3 = __uint_as_float(p3 & 0xFFFF0000u);
        a0.x += v0 * BF(x0.x); a0.y += v0 * BF(x0.y); a0.z += v0 * BF(x0.z); a0.w += v0 * BF(x0.w);
        a1.x += v1 * BF(x1.x); a1.y += v1 * BF(x1.y); a1.z += v1 * BF(x1.z); a1.w += v1 * BF(x1.w);
        a2.x += v2 * BF(x2.x); a2.y += v2 * BF(x2.y); a2.z += v2 * BF(x2.z); a2.w += v2 * BF(x2.w);
        a3.x += v3 * BF(x3.x); a3.y += v3 * BF(x3.y); a3.z += v3 * BF(x3.z); a3.w += v3 * BF(x3.w);
    }
    for (; i < L; i += 2) {
        int e = i + half;
        unsigned p = (e < L) ? pairs[s + e] : 0u;   // val=0 when OOB
        ushort4 xv = *reinterpret_cast<const ushort4*>(&Xb[(size_t)(p & 0xFFFFu) * D + cq]);
        float v = __uint_as_float(p & 0xFFFF0000u);
        a0.x += v * BF(xv.x); a0.y += v * BF(xv.y); a0.z += v * BF(xv.z); a0.w += v * BF(xv.w);
    }
#undef BF

    float4 A;
    A.x = (a0.x + a1.x) + (a2.x + a3.x);
    A.y = (a0.y + a1.y) + (a2.y + a3.y);
    A.z = (a0.z + a1.z) + (a2.z + a3.z);
    A.w = (a0.w + a1.w) + (a2.w + a3.w);
    A.x += __shfl_xor(A.x, 32);
    A.y += __shfl_xor(A.y, 32);
    A.z += __shfl_xor(A.z, 32);
    A.w += __shfl_xor(A.w, 32);
    if (half == 0)
        *reinterpret_cast<float4*>(&out[(size_t)row * D + cq]) = A;
}

// ---------------- atomic fallback (all-fp32 path) ----------------
__global__ __launch_bounds__(256) void spmm_atomic(
    const float* __restrict__ vals, const int* __restrict__ orow,
    const int* __restrict__ gcol, const float* __restrict__ Xm,
    float* __restrict__ outm, int nnz)
{
    const int gwave = (blockIdx.x * 256 + threadIdx.x) >> 6;
    const int lane = threadIdx.x & 63;
    const int e0 = gwave * 4;
#pragma unroll
    for (int i = 0; i < 4; ++i) {
        int e = e0 + i;
        if (e >= nnz) break;
        float v = vals[e];
        int r = orow[e];
        int c = gcol[e];
        float2 xv = *reinterpret_cast<const float2*>(&Xm[(size_t)c * D + lane * 2]);
        unsafeAtomicAdd(&outm[(size_t)r * D + lane * 2 + 0], v * xv.x);
        unsafeAtomicAdd(&outm[(size_t)r * D + lane * 2 + 1], v * xv.y);
    }
}

extern "C" void kernel_launch(void* const* d_in, const int* in_sizes, int n_in,
                              void* d_out, int out_size, void* d_ws, size_t ws_size,
                              hipStream_t stream) {
    const float* x      = (const float*)d_in[0];
    const float* y      = (const float*)d_in[1];
    const float* c      = (const float*)d_in[2];
    const float* b      = (const float*)d_in[3];
    const float* A_vals = (const float*)d_in[4];
    const int*   A_rows = (const int*)d_in[5];
    const int*   A_cols = (const int*)d_in[6];
    const float* Ukx_w  = (const float*)d_in[7];
    const float* Ukx_b  = (const float*)d_in[8];
    const float* Uky_w  = (const float*)d_in[9];
    const float* Uky_b  = (const float*)d_in[10];
    const float* tau    = (const float*)d_in[11];
    const float* Vky_w  = (const float*)d_in[12];
    const float* Vky_b  = (const float*)d_in[13];
    const float* Wkx_w  = (const float*)d_in[14];
    const float* Wkx_b  = (const float*)d_in[15];
    const float* Vkx_w  = (const float*)d_in[16];
    const float* Vkx_b  = (const float*)d_in[17];
    const float* sigma  = (const float*)d_in[18];

    const int N   = in_sizes[0] / D;        // 50000
    const int nnz = in_sizes[4];            // 1.6M
    const int nbk = (N + RB - 1) / RB;      // 782

    float* out_x = (float*)d_out;
    float* out_y = out_x + (size_t)N * D;

    const int gemm_grid = (N + 63) / 64;
    const int ggrid = (N + 3) / 4;

    // ws layout:
    //   region0 (transient union): recR|recC (2*nnz int2)  OR  tmp (zxb bf16 / fp32 fallback)
    //   persistent: UkyT|UkxT|VkyT|WcT|bc | pairsR|pairsC (2*nnz u32) |
    //               cntR,cntC,goffR,goffC (4*nbk) | offR,lenR,offC,lenC (4*N)
    //   h/rs (2*CH*nbk ints) ALIASES the head of pairsR (dead before sort writes)
    //   uyb (bf16 N*D) lives in the out_y half of d_out (dead before y_new write)
    const size_t pool = (size_t)nnz;
    char* base = (char*)d_ws;
    float* tmp = (float*)base;
    int2* recR = (int2*)base;
    int2* recC = recR + pool;
    size_t region0 = (size_t)N * D * 4;
    if (2 * pool * 8 > region0) region0 = 2 * pool * 8;
    char* pers = base + region0;
    float* UkyT = (float*)pers;
    float* UkxT = UkyT + D * D;
    float* VkyT = UkxT + D * D;
    float* WcT  = VkyT + D * D;
    float* bc   = WcT + D * D;
    unsigned* pairsR = (unsigned*)(bc + D);
    unsigned* pairsC = pairsR + pool;
    int* cntR  = (int*)(pairsC + pool);
    int* cntC  = cntR + nbk;
    int* goffR = cntC + nbk;
    int* goffC = goffR + nbk;
    int* offR  = goffC + nbk;
    int* lenR  = offR + N;
    int* offC  = lenR + N;
    int* lenC  = offC + N;
    int* hR = (int*)pairsR;                 // aliases pairsR head (2*CH*nbk ints)
    int* hC = hR + (size_t)CH * nbk;

    unsigned short* uyb = (unsigned short*)out_y;   // bf16 uy in out_y half
    unsigned short* zxb = (unsigned short*)tmp;     // bf16 zx in region0

    size_t need = region0 + (4 * (size_t)D * D + D) * 4 + 2 * pool * 4
                + (4 * (size_t)nbk + 4 * (size_t)N) * 4;
    bool h_fits = (size_t)2 * CH * nbk * 4 <= pool * 4;

    setup_weights<<<4, 256, 0, stream>>>(Uky_w, Ukx_w, Vky_w, Vkx_w, Wkx_w,
                                         Vkx_b, Wkx_b, UkyT, UkxT, VkyT, WcT, bc);

    if (N < 65536 && nbk <= NBKMAX && ws_size >= need && h_fits) {
        const int ce = (nnz + CH - 1) / CH;

        // ---- radix-style build (no global atomics) ----
        {
            dim3 g1(CH, 2);
            hist_chunks<<<g1, 256, 0, stream>>>(A_rows, A_cols, hR, hC, nnz, nbk, ce);
            dim3 g2(nbk, 2);
            bucket_tot<<<g2, 256, 0, stream>>>(hR, hC, cntR, cntC, nbk);
            scan_buckets<<<2, 256, 0, stream>>>(cntR, cntC, goffR, goffC, nbk);
            runstarts<<<g2, 256, 0, stream>>>(hR, hC, goffR, goffC, nbk);
            scatter_chunks<<<CH, 256, 0, stream>>>(A_rows, A_cols, A_vals,
                                                   hR, recR, hC, recC, nnz, nbk, ce);
            sort_buckets<<<g2, 256, 0, stream>>>(recR, recC, goffR, cntR, goffC, cntC,
                                                 pairsR, pairsC, offR, lenR, offC, lenC, N);
        }

        // uy = y @ Uky^T + b  -> bf16 in out_y half (dead before y_new write)
        gemm_v2<0, 1><<<gemm_grid, 256, 0, stream>>>(y, UkyT, Uky_b, nullptr, nullptr, nullptr,
                                                     (float*)uyb, N);
        // at_uy -> out_x   (grouped by A_cols; gather col = A_rows)
        spmm_pairs_v3<<<ggrid, 256, 0, stream>>>(pairsC, offC, lenC, uyb, out_x, N);
        // x_new -> out_x (in place)
        gemm_v2<1, 0><<<gemm_grid, 256, 0, stream>>>(x, UkxT, Ukx_b, c, out_x, tau, out_x, N);
        // zx -> bf16 in tmp (records are dead now)
        gemm_v2<0, 1><<<gemm_grid, 256, 0, stream>>>(out_x, WcT, bc, nullptr, nullptr, nullptr,
                                                     (float*)zxb, N);
        // az -> out_y   (grouped by A_rows; gather col = A_cols)
        spmm_pairs_v3<<<ggrid, 256, 0, stream>>>(pairsR, offR, lenR, zxb, out_y, N);
        // y_new -> out_y (in place)
        gemm_v2<2, 0><<<gemm_grid, 256, 0, stream>>>(y, VkyT, Vky_b, b, out_y, sigma, out_y, N);
    } else {
        // ---- atomic fallback (all fp32) ----
        const int spmm_grid = (nnz + 15) / 16;
        gemm_v2<0, 0><<<gemm_grid, 256, 0, stream>>>(y, UkyT, Uky_b, nullptr, nullptr, nullptr, tmp, N);
        hipMemsetAsync(out_x, 0, (size_t)N * D * sizeof(float), stream);
        spmm_atomic<<<spmm_grid, 256, 0, stream>>>(A_vals, A_cols, A_rows, tmp, out_x, nnz);
        gemm_v2<1, 0><<<gemm_grid, 256, 0, stream>>>(x, UkxT, Ukx_b, c, out_x, tau, out_x, N);
        gemm_v2<0, 0><<<gemm_grid, 256, 0, stream>>>(out_x, WcT, bc, nullptr, nullptr, nullptr, tmp, N);
        hipMemsetAsync(out_y, 0, (size_t)N * D * sizeof(float), stream);
        spmm_atomic<<<spmm_grid, 256, 0, stream>>>(A_vals, A_rows, A_cols, tmp, out_y, nnz);
        gemm_v2<2, 0><<<gemm_grid, 256, 0, stream>>>(y, VkyT, Vky_b, b, out_y, sigma, out_y, N);
    }
}

// Round 10
// 293.880 us; speedup vs baseline: 10.0577x; 1.1230x over previous
//
#include <hip/hip_runtime.h>

#define D 128
#define RB 64           // rows per bucket
#define NBKMAX 1024     // max buckets (N <= 65536)
#define CH 256          // edge chunks

typedef __attribute__((ext_vector_type(4))) float f32x4;
typedef __attribute__((ext_vector_type(8))) short bf16x8;

__device__ __forceinline__ unsigned short bf16r(float f) {
    unsigned b = __float_as_uint(f);
    return (unsigned short)((b + 0x7FFFu + ((b >> 16) & 1u)) >> 16);
}

// ---------------- setup: fp32 WT (fallback) + bf16 Wb (MFMA path) -----------------
// m 0-3: fp32 transposed WT ; m 4-7: bf16 rounded original-layout Wb
__global__ __launch_bounds__(256) void setup_weights(
    const float* __restrict__ Uky, const float* __restrict__ Ukx,
    const float* __restrict__ Vky, const float* __restrict__ Vkx,
    const float* __restrict__ Wkx, const float* __restrict__ Vkx_b,
    const float* __restrict__ Wkx_b,
    float* __restrict__ UkyT, float* __restrict__ UkxT,
    float* __restrict__ VkyT, float* __restrict__ WcT,
    unsigned short* __restrict__ UkyB, unsigned short* __restrict__ UkxB,
    unsigned short* __restrict__ VkyB, unsigned short* __restrict__ WcB,
    float* __restrict__ bc)
{
    const int m = blockIdx.x;
    if (m < 4) {
        const float* src = (m == 0) ? Uky : (m == 1) ? Ukx : (m == 2) ? Vky : nullptr;
        float* dst = (m == 0) ? UkyT : (m == 1) ? UkxT : (m == 2) ? VkyT : WcT;
        for (int i = threadIdx.x; i < D * D; i += 256) {
            int k = i >> 7, d = i & 127;
            float v;
            if (m == 3) v = Vkx[d * D + k] - 2.0f * Wkx[d * D + k];
            else        v = src[d * D + k];
            dst[i] = v;   // dst[k][d]
        }
        if (m == 3 && threadIdx.x < D)
            bc[threadIdx.x] = Vkx_b[threadIdx.x] - 2.0f * Wkx_b[threadIdx.x];
    } else {
        const int mm = m - 4;
        const float* src = (mm == 0) ? Uky : (mm == 1) ? Ukx : (mm == 2) ? Vky : nullptr;
        unsigned short* dst = (mm == 0) ? UkyB : (mm == 1) ? UkxB : (mm == 2) ? VkyB : WcB;
        for (int i = threadIdx.x; i < D * D; i += 256) {
            float v;
            if (mm == 3) v = Vkx[i] - 2.0f * Wkx[i];
            else         v = src[i];
            dst[i] = bf16r(v);   // original [n][k] layout == B-fragment layout
        }
    }
}

// ---------------- MFMA GEMM: out = epi(X @ W^T + bias), bf16 inputs fp32 acc ------
// block = 256 thr (4 waves) x 64-row tile; wave w owns rows w*16..w*16+15, all 128 cols.
// Wb is bf16 in ORIGINAL [n][k] layout (B[k][n] = W[n][k] -> k-contiguous fragments).
template <int EPI, int OB16>
__global__ __launch_bounds__(256) void gemm_mfma(
    const float* __restrict__ X, const unsigned short* __restrict__ Wb,
    const float* __restrict__ bias, const float* __restrict__ colvec,
    const float* __restrict__ spout, const float* __restrict__ scal,
    float* __restrict__ out, int N)
{
    __shared__ __align__(16) unsigned short Xs[64 * 128];   // bf16, XOR-swizzled rows
    const int t = threadIdx.x;
    const int block_row = blockIdx.x * 64;

    // stage X (fp32 -> bf16), swizzle bits 4-6 of in-row byte offset by (row&7)<<4
#pragma unroll
    for (int i = 0; i < 8; ++i) {
        int f = t + i * 256;          // 2048 float4
        int r = f >> 5;               // 0..63
        int k4 = (f & 31) << 2;       // 0..124
        float4 g = make_float4(0.f, 0.f, 0.f, 0.f);
        int row = block_row + r;
        if (row < N) g = *reinterpret_cast<const float4*>(&X[(size_t)row * D + k4]);
        ushort4 h;
        h.x = bf16r(g.x); h.y = bf16r(g.y); h.z = bf16r(g.z); h.w = bf16r(g.w);
        unsigned byte = (unsigned)(k4 * 2) ^ ((unsigned)(r & 7) << 4);
        *reinterpret_cast<ushort4*>((char*)Xs + r * 256 + byte) = h;
    }
    __syncthreads();

    const int w  = t >> 6;
    const int l  = t & 63;
    const int lr = l & 15;     // A-row-in-16 / B-col-in-16 / D-col-in-16
    const int lq = l >> 4;     // quarter 0..3

    f32x4 acc[8];
#pragma unroll
    for (int nt = 0; nt < 8; ++nt) acc[nt] = (f32x4)(0.f);

    const int arow = w * 16 + lr;   // local row for A fragment

#pragma unroll
    for (int kc = 0; kc < 4; ++kc) {
        // A frag: Xs[arow][kc*32 + lq*8 .. +7]  (16B, swizzled -> 2-way max)
        unsigned abyte = ((unsigned)(kc * 64 + lq * 16)) ^ ((unsigned)(arow & 7) << 4);
        bf16x8 a = *reinterpret_cast<const bf16x8*>((const char*)Xs + arow * 256 + abyte);
#pragma unroll
        for (int nt = 0; nt < 8; ++nt) {
            // B frag: B[k = kc*32+lq*8+j][n = nt*16+lr] = Wb[n][k], k-contiguous 16B
            bf16x8 b = *reinterpret_cast<const bf16x8*>(
                &Wb[(size_t)(nt * 16 + lr) * D + kc * 32 + lq * 8]);
            acc[nt] = __builtin_amdgcn_mfma_f32_16x16x32_bf16(a, b, acc[nt], 0, 0, 0);
        }
    }

    // epilogue: D[row=(lq*4+r)][col=lr] per 16x16 tile (m89-verified layout)
    const float sc = (EPI == 0) ? 0.f : scal[0];
    float bs[8];
#pragma unroll
    for (int nt = 0; nt < 8; ++nt) bs[nt] = bias[nt * 16 + lr];

#pragma unroll
    for (int r = 0; r < 4; ++r) {
        const int row = block_row + w * 16 + lq * 4 + r;
        if (row >= N) continue;
        const float cv = (EPI == 0) ? 0.f : colvec[row];
#pragma unroll
        for (int nt = 0; nt < 8; ++nt) {
            const int col = nt * 16 + lr;
            float res = acc[nt][r] + bs[nt];
            if (EPI == 1) {
                float sp = spout[(size_t)row * D + col];
                res = fmaxf(res - sc * (cv - sp), 0.f);
            } else if (EPI == 2) {
                float sp = spout[(size_t)row * D + col];
                res = fmaxf(res - sc * (cv + sp), 0.f);
            }
            if (OB16) ((unsigned short*)out)[(size_t)row * D + col] = bf16r(res);
            else      out[(size_t)row * D + col] = res;
        }
    }
}

// ---------------- fp32 GEMM (fallback path only) ----------------
template <int EPI>
__global__ __launch_bounds__(256) void gemm_v2(
    const float* __restrict__ X, const float* __restrict__ WT,
    const float* __restrict__ bias, const float* __restrict__ colvec,
    const float* __restrict__ spout, const float* __restrict__ scal,
    float* __restrict__ out, int N)
{
    __shared__ float Xsf[64][D + 4];
    __shared__ float Wt[64][D + 4];
    const int t = threadIdx.x;
    const int block_row = blockIdx.x * 64;

#pragma unroll
    for (int i = 0; i < 8; ++i) {
        int f = t + i * 256;
        int r = f >> 5;
        int k4 = (f & 31) << 2;
        float4 g = make_float4(0.f, 0.f, 0.f, 0.f);
        int row = block_row + r;
        if (row < N) g = *reinterpret_cast<const float4*>(&X[(size_t)row * D + k4]);
        *reinterpret_cast<float4*>(&Xsf[r][k4]) = g;
    }

    const int cg = t & 15;
    const int rp = t >> 4;
    const int r0 = rp * 4;
    const int c0 = cg * 4, c1 = 64 + cg * 4;
    float acc[4][8] = {{0.f}};

    for (int kb = 0; kb < D; kb += 64) {
        __syncthreads();
#pragma unroll
        for (int i = 0; i < 8; ++i) {
            int f = t + i * 256;
            int kk = f >> 5;
            int d4 = (f & 31) << 2;
            float4 g = *reinterpret_cast<const float4*>(&WT[(size_t)(kb + kk) * D + d4]);
            *reinterpret_cast<float4*>(&Wt[kk][d4]) = g;
        }
        __syncthreads();
#pragma unroll 2
        for (int k4 = 0; k4 < 64; k4 += 4) {
            float4 xr[4];
#pragma unroll
            for (int j = 0; j < 4; ++j)
                xr[j] = *reinterpret_cast<const float4*>(&Xsf[r0 + j][kb + k4]);
#pragma unroll
            for (int q = 0; q < 4; ++q) {
                const float4 w0 = *reinterpret_cast<const float4*>(&Wt[k4 + q][c0]);
                const float4 w1 = *reinterpret_cast<const float4*>(&Wt[k4 + q][c1]);
#pragma unroll
                for (int j = 0; j < 4; ++j) {
                    const float xv = (q == 0) ? xr[j].x : (q == 1) ? xr[j].y
                                   : (q == 2) ? xr[j].z : xr[j].w;
                    acc[j][0] += xv * w0.x; acc[j][1] += xv * w0.y;
                    acc[j][2] += xv * w0.z; acc[j][3] += xv * w0.w;
                    acc[j][4] += xv * w1.x; acc[j][5] += xv * w1.y;
                    acc[j][6] += xv * w1.z; acc[j][7] += xv * w1.w;
                }
            }
        }
    }

    const float sc = (EPI == 0) ? 0.f : scal[0];
    const float4 bias0 = *reinterpret_cast<const float4*>(&bias[c0]);
    const float4 bias1 = *reinterpret_cast<const float4*>(&bias[c1]);

#pragma unroll
    for (int j = 0; j < 4; ++j) {
        const int row = block_row + r0 + j;
        if (row >= N) continue;
        const float cv = (EPI == 0) ? 0.f : colvec[row];
#pragma unroll
        for (int h = 0; h < 2; ++h) {
            const int col = (h == 0) ? c0 : c1;
            const float4 bsv = (h == 0) ? bias0 : bias1;
            float4 res;
            res.x = acc[j][h * 4 + 0] + bsv.x;
            res.y = acc[j][h * 4 + 1] + bsv.y;
            res.z = acc[j][h * 4 + 2] + bsv.z;
            res.w = acc[j][h * 4 + 3] + bsv.w;
            if (EPI == 1) {
                float4 sp = *reinterpret_cast<const float4*>(&spout[(size_t)row * D + col]);
                res.x = fmaxf(res.x - sc * (cv - sp.x), 0.f);
                res.y = fmaxf(res.y - sc * (cv - sp.y), 0.f);
                res.z = fmaxf(res.z - sc * (cv - sp.z), 0.f);
                res.w = fmaxf(res.w - sc * (cv - sp.w), 0.f);
            } else if (EPI == 2) {
                float4 sp = *reinterpret_cast<const float4*>(&spout[(size_t)row * D + col]);
                res.x = fmaxf(res.x - sc * (cv + sp.x), 0.f);
                res.y = fmaxf(res.y - sc * (cv + sp.y), 0.f);
                res.z = fmaxf(res.z - sc * (cv + sp.z), 0.f);
                res.w = fmaxf(res.w - sc * (cv + sp.w), 0.f);
            }
            *reinterpret_cast<float4*>(&out[(size_t)row * D + col]) = res;
        }
    }
}

// ---------------- K1: per-chunk bucket histogram ----------------
__global__ __launch_bounds__(256) void hist_chunks(
    const int* __restrict__ rows, const int* __restrict__ cols,
    int* __restrict__ hR, int* __restrict__ hC, int nnz, int nbk, int ce)
{
    __shared__ int lh[NBKMAX];
    const int chunk = blockIdx.x;
    const bool isC = blockIdx.y;
    const int* idx = isC ? cols : rows;
    int* hout = (isC ? hC : hR) + (size_t)chunk * nbk;
    for (int i = threadIdx.x; i < nbk; i += 256) lh[i] = 0;
    __syncthreads();
    const int e0 = chunk * ce, e1 = min(nnz, e0 + ce);
    for (int e = e0 + threadIdx.x; e < e1; e += 256)
        atomicAdd(&lh[idx[e] >> 6], 1);
    __syncthreads();
    for (int i = threadIdx.x; i < nbk; i += 256) hout[i] = lh[i];
}

// ---------------- K2: bucket totals ----------------
__global__ __launch_bounds__(256) void bucket_tot(
    const int* __restrict__ hR, const int* __restrict__ hC,
    int* __restrict__ cntR, int* __restrict__ cntC, int nbk)
{
    const int b = blockIdx.x;
    const bool isC = blockIdx.y;
    const int* h = (isC ? hC : hR);
    __shared__ int s[256];
    int v = h[(size_t)threadIdx.x * nbk + b];
    s[threadIdx.x] = v;
    __syncthreads();
#pragma unroll
    for (int d = 128; d > 0; d >>= 1) {
        if (threadIdx.x < d) s[threadIdx.x] += s[threadIdx.x + d];
        __syncthreads();
    }
    if (threadIdx.x == 0) (isC ? cntC : cntR)[b] = s[0];
}

// ---------------- K3: bucket scan -> goff ----------------
__global__ __launch_bounds__(256) void scan_buckets(
    const int* __restrict__ cntR, const int* __restrict__ cntC,
    int* __restrict__ goffR, int* __restrict__ goffC, int nbk)
{
    const int* cnt = blockIdx.x ? cntC : cntR;
    int* goff = blockIdx.x ? goffC : goffR;
    __shared__ int s[256];
    const int t = threadIdx.x;
    const int base = t * 4;
    int loc[4]; int sum = 0;
#pragma unroll
    for (int u = 0; u < 4; ++u) {
        int idx = base + u;
        int v = (idx < nbk) ? cnt[idx] : 0;
        loc[u] = sum; sum += v;
    }
    s[t] = sum;
    __syncthreads();
#pragma unroll
    for (int d = 1; d < 256; d <<= 1) {
        int tv = (t >= d) ? s[t - d] : 0;
        __syncthreads();
        s[t] += tv;
        __syncthreads();
    }
    int excl = s[t] - sum;
#pragma unroll
    for (int u = 0; u < 4; ++u) {
        int idx = base + u;
        if (idx < nbk) goff[idx] = excl + loc[u];
    }
}

// ---------------- K4: run starts (in-place h -> rs) ----------------
__global__ __launch_bounds__(256) void runstarts(
    int* __restrict__ hR, int* __restrict__ hC,
    const int* __restrict__ goffR, const int* __restrict__ goffC, int nbk)
{
    const int b = blockIdx.x;
    const bool isC = blockIdx.y;
    int* h = (isC ? hC : hR);
    const int g0 = (isC ? goffC : goffR)[b];
    __shared__ int s[256];
    const int t = threadIdx.x;
    int v = h[(size_t)t * nbk + b];
    s[t] = v;
    __syncthreads();
#pragma unroll
    for (int d = 1; d < 256; d <<= 1) {
        int tv = (t >= d) ? s[t - d] : 0;
        __syncthreads();
        s[t] += tv;
        __syncthreads();
    }
    h[(size_t)t * nbk + b] = g0 + s[t] - v;
}

// ---------------- K5: scatter with LDS cursors (1024 thr for occupancy) -----------
__global__ __launch_bounds__(1024) void scatter_chunks(
    const int* __restrict__ rows, const int* __restrict__ cols,
    const float* __restrict__ vals,
    const int* __restrict__ rsR, int2* __restrict__ recR,
    const int* __restrict__ rsC, int2* __restrict__ recC,
    int nnz, int nbk, int ce)
{
    __shared__ int lrsR[NBKMAX], lcurR[NBKMAX];
    __shared__ int lrsC[NBKMAX], lcurC[NBKMAX];
    const int chunk = blockIdx.x;
    for (int i = threadIdx.x; i < nbk; i += 1024) {
        lrsR[i] = rsR[(size_t)chunk * nbk + i]; lcurR[i] = 0;
        lrsC[i] = rsC[(size_t)chunk * nbk + i]; lcurC[i] = 0;
    }
    __syncthreads();
    const int e0 = chunk * ce, e1 = min(nnz, e0 + ce);
    for (int e = e0 + threadIdx.x; e < e1; e += 1024) {
        int r = rows[e], c = cols[e];
        int vb = __float_as_int(vals[e]);
        int bR = r >> 6, bC = c >> 6;
        int pR = lrsR[bR] + atomicAdd(&lcurR[bR], 1);
        recR[pR] = make_int2(((r & 63) << 16) | c, vb);
        int pC = lrsC[bC] + atomicAdd(&lcurC[bC], 1);
        recC[pC] = make_int2(((c & 63) << 16) | r, vb);
    }
}

// ---------------- per-bucket row sort -> packed 4B pairs ----------------
__global__ __launch_bounds__(256) void sort_buckets(
    const int2* __restrict__ recR, const int2* __restrict__ recC,
    const int* __restrict__ goffR, const int* __restrict__ cntR,
    const int* __restrict__ goffC, const int* __restrict__ cntC,
    unsigned* __restrict__ pairsR, unsigned* __restrict__ pairsC,
    int* __restrict__ offR, int* __restrict__ lenR,
    int* __restrict__ offC, int* __restrict__ lenC, int N)
{
    const bool isC = blockIdx.y;
    const int b = blockIdx.x;
    const int2* rec = isC ? recC : recR;
    unsigned* pairs = isC ? pairsC : pairsR;
    int* off = isC ? offC : offR;
    int* len = isC ? lenC : lenR;
    const int s = (isC ? goffC : goffR)[b];
    const int L = (isC ? cntC : cntR)[b];
    const int t = threadIdx.x;

    __shared__ int lcnt[RB], lpos[RB], lcur[RB];
    if (t < RB) lcnt[t] = 0;
    __syncthreads();
    for (int i = t; i < L; i += 256)
        atomicAdd(&lcnt[rec[s + i].x >> 16], 1);
    __syncthreads();
    if (t == 0) {
        int run = 0;
#pragma unroll
        for (int r = 0; r < RB; ++r) { lpos[r] = run; run += lcnt[r]; }
    }
    __syncthreads();
    if (t < RB) {
        int row = b * RB + t;
        if (row < N) { off[row] = s + lpos[t]; len[row] = lcnt[t]; }
        lcur[t] = 0;
    }
    __syncthreads();
    for (int i = t; i < L; i += 256) {
        int2 pr = rec[s + i];
        int r = pr.x >> 16;
        int p = lpos[r] + atomicAdd(&lcur[r], 1);
        unsigned vb = (unsigned)pr.y;
        unsigned v16 = (vb + 0x7FFFu + ((vb >> 16) & 1u)) >> 16;
        pairs[s + p] = (v16 << 16) | (unsigned)(pr.x & 0xFFFF);
    }
}

// ---------------- pairs-gather SpMM v3: bf16 X, packed 4B pairs ----------------
__global__ __launch_bounds__(256) void spmm_pairs_v3(
    const unsigned* __restrict__ pairs, const int* __restrict__ off,
    const int* __restrict__ len, const unsigned short* __restrict__ Xb,
    float* __restrict__ out, int N)
{
    const int row = (blockIdx.x * 256 + threadIdx.x) >> 6;
    if (row >= N) return;
    const int lane = threadIdx.x & 63;
    const int half = lane >> 5;
    const int cq = (lane & 31) << 2;
    const int s = off[row];
    const int L = len[row];

    float4 a0 = make_float4(0.f, 0.f, 0.f, 0.f);
    float4 a1 = make_float4(0.f, 0.f, 0.f, 0.f);
    float4 a2 = make_float4(0.f, 0.f, 0.f, 0.f);
    float4 a3 = make_float4(0.f, 0.f, 0.f, 0.f);

#define BF(u) __uint_as_float((unsigned)(u) << 16)
    int i = 0;
    for (; i + 7 < L; i += 8) {
        unsigned p0 = pairs[s + i + 0 + half];
        unsigned p1 = pairs[s + i + 2 + half];
        unsigned p2 = pairs[s + i + 4 + half];
        unsigned p3 = pairs[s + i + 6 + half];
        ushort4 x0 = *reinterpret_cast<const ushort4*>(&Xb[(size_t)(p0 & 0xFFFFu) * D + cq]);
        ushort4 x1 = *reinterpret_cast<const ushort4*>(&Xb[(size_t)(p1 & 0xFFFFu) * D + cq]);
        ushort4 x2 = *reinterpret_cast<const ushort4*>(&Xb[(size_t)(p2 & 0xFFFFu) * D + cq]);
        ushort4 x3 = *reinterpret_cast<const ushort4*>(&Xb[(size_t)(p3 & 0xFFFFu) * D + cq]);
        float v0 = __uint_as_float(p0 & 0xFFFF0000u);
        float v1 = __uint_as_float(p1 & 0xFFFF0000u);
        float v2 = __uint_as_float(p2 & 0xFFFF0000u);
        float v3 = __uint_as_float(p3 & 0xFFFF0000u);
        a0.x += v0 * BF(x0.x); a0.y += v0 * BF(x0.y); a0.z += v0 * BF(x0.z); a0.w += v0 * BF(x0.w);
        a1.x += v1 * BF(x1.x); a1.y += v1 * BF(x1.y); a1.z += v1 * BF(x1.z); a1.w += v1 * BF(x1.w);
        a2.x += v2 * BF(x2.x); a2.y += v2 * BF(x2.y); a2.z += v2 * BF(x2.z); a2.w += v2 * BF(x2.w);
        a3.x += v3 * BF(x3.x); a3.y += v3 * BF(x3.y); a3.z += v3 * BF(x3.z); a3.w += v3 * BF(x3.w);
    }
    for (; i < L; i += 2) {
        int e = i + half;
        unsigned p = (e < L) ? pairs[s + e] : 0u;
        ushort4 xv = *reinterpret_cast<const ushort4*>(&Xb[(size_t)(p & 0xFFFFu) * D + cq]);
        float v = __uint_as_float(p & 0xFFFF0000u);
        a0.x += v * BF(xv.x); a0.y += v * BF(xv.y); a0.z += v * BF(xv.z); a0.w += v * BF(xv.w);
    }
#undef BF

    float4 A;
    A.x = (a0.x + a1.x) + (a2.x + a3.x);
    A.y = (a0.y + a1.y) + (a2.y + a3.y);
    A.z = (a0.z + a1.z) + (a2.z + a3.z);
    A.w = (a0.w + a1.w) + (a2.w + a3.w);
    A.x += __shfl_xor(A.x, 32);
    A.y += __shfl_xor(A.y, 32);
    A.z += __shfl_xor(A.z, 32);
    A.w += __shfl_xor(A.w, 32);
    if (half == 0)
        *reinterpret_cast<float4*>(&out[(size_t)row * D + cq]) = A;
}

// ---------------- atomic fallback ----------------
__global__ __launch_bounds__(256) void spmm_atomic(
    const float* __restrict__ vals, const int* __restrict__ orow,
    const int* __restrict__ gcol, const float* __restrict__ Xm,
    float* __restrict__ outm, int nnz)
{
    const int gwave = (blockIdx.x * 256 + threadIdx.x) >> 6;
    const int lane = threadIdx.x & 63;
    const int e0 = gwave * 4;
#pragma unroll
    for (int i = 0; i < 4; ++i) {
        int e = e0 + i;
        if (e >= nnz) break;
        float v = vals[e];
        int r = orow[e];
        int c = gcol[e];
        float2 xv = *reinterpret_cast<const float2*>(&Xm[(size_t)c * D + lane * 2]);
        unsafeAtomicAdd(&outm[(size_t)r * D + lane * 2 + 0], v * xv.x);
        unsafeAtomicAdd(&outm[(size_t)r * D + lane * 2 + 1], v * xv.y);
    }
}

extern "C" void kernel_launch(void* const* d_in, const int* in_sizes, int n_in,
                              void* d_out, int out_size, void* d_ws, size_t ws_size,
                              hipStream_t stream) {
    const float* x      = (const float*)d_in[0];
    const float* y      = (const float*)d_in[1];
    const float* c      = (const float*)d_in[2];
    const float* b      = (const float*)d_in[3];
    const float* A_vals = (const float*)d_in[4];
    const int*   A_rows = (const int*)d_in[5];
    const int*   A_cols = (const int*)d_in[6];
    const float* Ukx_w  = (const float*)d_in[7];
    const float* Ukx_b  = (const float*)d_in[8];
    const float* Uky_w  = (const float*)d_in[9];
    const float* Uky_b  = (const float*)d_in[10];
    const float* tau    = (const float*)d_in[11];
    const float* Vky_w  = (const float*)d_in[12];
    const float* Vky_b  = (const float*)d_in[13];
    const float* Wkx_w  = (const float*)d_in[14];
    const float* Wkx_b  = (const float*)d_in[15];
    const float* Vkx_w  = (const float*)d_in[16];
    const float* Vkx_b  = (const float*)d_in[17];
    const float* sigma  = (const float*)d_in[18];

    const int N   = in_sizes[0] / D;        // 50000
    const int nnz = in_sizes[4];            // 1.6M
    const int nbk = (N + RB - 1) / RB;      // 782

    float* out_x = (float*)d_out;
    float* out_y = out_x + (size_t)N * D;

    const int gemm_grid = (N + 63) / 64;
    const int ggrid = (N + 3) / 4;

    // ws layout:
    //   region0 (transient union): recR|recC (2*nnz int2)  OR  tmp (zxb bf16 / fp32 fallback)
    //   persistent: UkyT|UkxT|VkyT|WcT (fp32) | UkyB|UkxB|VkyB|WcB (bf16) | bc |
    //               pairsR|pairsC (2*nnz u32) | cnt/goff (4*nbk) | off/len (4*N)
    //   h/rs (2*CH*nbk ints) aliases pairsR head; uyb (bf16) lives in out_y half
    const size_t pool = (size_t)nnz;
    char* base = (char*)d_ws;
    float* tmp = (float*)base;
    int2* recR = (int2*)base;
    int2* recC = recR + pool;
    size_t region0 = (size_t)N * D * 4;
    if (2 * pool * 8 > region0) region0 = 2 * pool * 8;
    char* pers = base + region0;
    float* UkyT = (float*)pers;
    float* UkxT = UkyT + D * D;
    float* VkyT = UkxT + D * D;
    float* WcT  = VkyT + D * D;
    unsigned short* UkyB = (unsigned short*)(WcT + D * D);
    unsigned short* UkxB = UkyB + D * D;
    unsigned short* VkyB = UkxB + D * D;
    unsigned short* WcB  = VkyB + D * D;
    float* bc = (float*)(WcB + D * D);
    unsigned* pairsR = (unsigned*)(bc + D);
    unsigned* pairsC = pairsR + pool;
    int* cntR  = (int*)(pairsC + pool);
    int* cntC  = cntR + nbk;
    int* goffR = cntC + nbk;
    int* goffC = goffR + nbk;
    int* offR  = goffC + nbk;
    int* lenR  = offR + N;
    int* offC  = lenR + N;
    int* lenC  = offC + N;
    int* hR = (int*)pairsR;
    int* hC = hR + (size_t)CH * nbk;

    unsigned short* uyb = (unsigned short*)out_y;
    unsigned short* zxb = (unsigned short*)tmp;

    size_t need = region0 + (4 * (size_t)D * D + D) * 4 + 4 * (size_t)D * D * 2
                + 2 * pool * 4 + (4 * (size_t)nbk + 4 * (size_t)N) * 4;
    bool h_fits = (size_t)2 * CH * nbk * 4 <= pool * 4;

    setup_weights<<<8, 256, 0, stream>>>(Uky_w, Ukx_w, Vky_w, Vkx_w, Wkx_w,
                                         Vkx_b, Wkx_b, UkyT, UkxT, VkyT, WcT,
                                         UkyB, UkxB, VkyB, WcB, bc);

    if (N < 65536 && nbk <= NBKMAX && ws_size >= need && h_fits) {
        const int ce = (nnz + CH - 1) / CH;

        // ---- radix-style build (no global atomics) ----
        {
            dim3 g1(CH, 2);
            hist_chunks<<<g1, 256, 0, stream>>>(A_rows, A_cols, hR, hC, nnz, nbk, ce);
            dim3 g2(nbk, 2);
            bucket_tot<<<g2, 256, 0, stream>>>(hR, hC, cntR, cntC, nbk);
            scan_buckets<<<2, 256, 0, stream>>>(cntR, cntC, goffR, goffC, nbk);
            runstarts<<<g2, 256, 0, stream>>>(hR, hC, goffR, goffC, nbk);
            scatter_chunks<<<CH, 1024, 0, stream>>>(A_rows, A_cols, A_vals,
                                                    hR, recR, hC, recC, nnz, nbk, ce);
            sort_buckets<<<g2, 256, 0, stream>>>(recR, recC, goffR, cntR, goffC, cntC,
                                                 pairsR, pairsC, offR, lenR, offC, lenC, N);
        }

        // uy = y @ Uky^T + b  -> bf16 in out_y half (dead before y_new write)
        gemm_mfma<0, 1><<<gemm_grid, 256, 0, stream>>>(y, UkyB, Uky_b, nullptr, nullptr, nullptr,
                                                       (float*)uyb, N);
        // at_uy -> out_x
        spmm_pairs_v3<<<ggrid, 256, 0, stream>>>(pairsC, offC, lenC, uyb, out_x, N);
        // x_new -> out_x (in place)
        gemm_mfma<1, 0><<<gemm_grid, 256, 0, stream>>>(x, UkxB, Ukx_b, c, out_x, tau, out_x, N);
        // zx -> bf16 in tmp (records dead)
        gemm_mfma<0, 1><<<gemm_grid, 256, 0, stream>>>(out_x, WcB, bc, nullptr, nullptr, nullptr,
                                                       (float*)zxb, N);
        // az -> out_y
        spmm_pairs_v3<<<ggrid, 256, 0, stream>>>(pairsR, offR, lenR, zxb, out_y, N);
        // y_new -> out_y (in place)
        gemm_mfma<2, 0><<<gemm_grid, 256, 0, stream>>>(y, VkyB, Vky_b, b, out_y, sigma, out_y, N);
    } else {
        // ---- atomic fallback (all fp32) ----
        const int spmm_grid = (nnz + 15) / 16;
        gemm_v2<0><<<gemm_grid, 256, 0, stream>>>(y, UkyT, Uky_b, nullptr, nullptr, nullptr, tmp, N);
        hipMemsetAsync(out_x, 0, (size_t)N * D * sizeof(float), stream);
        spmm_atomic<<<spmm_grid, 256, 0, stream>>>(A_vals, A_cols, A_rows, tmp, out_x, nnz);
        gemm_v2<1><<<gemm_grid, 256, 0, stream>>>(x, UkxT, Ukx_b, c, out_x, tau, out_x, N);
        gemm_v2<0><<<gemm_grid, 256, 0, stream>>>(out_x, WcT, bc, nullptr, nullptr, nullptr, tmp, N);
        hipMemsetAsync(out_y, 0, (size_t)N * D * sizeof(float), stream);
        spmm_atomic<<<spmm_grid, 256, 0, stream>>>(A_vals, A_rows, A_cols, tmp, out_y, nnz);
        gemm_v2<2><<<gemm_grid, 256, 0, stream>>>(y, VkyT, Vky_b, b, out_y, sigma, out_y, N);
    }
}